// Round 12
// baseline (282.493 us; speedup 1.0000x reference)
//
#include <hip/hip_runtime.h>

// out[n, u*4+s] = sum_{e: dst[e]==n} x[src[e], u] * sh[e, s]
// N=100000, U=32, S=4, E=3200000.
//
// Ledger of lessons:
//  R2: bulk LDS float atomics = ~1 lane/cycle serial floor -> register accum.
//  R4/R5/R7: scattered writes into >~400 streams/block = 4.3x HBM write amp.
//  R8: few deep-serial blocks (17% occ) lose to 100k shallow blocks.
//  R9: xb gather is L3-served (6.4MB > 4MB per-XCD L2, uniform access).
//  R10: NT loads on broadcast/shared streams re-fetch lines (FETCH +11MB).
//  R11: contiguous per-lane ranges + independent gathers in flight -> -30%.
// R12: accum lane remap: 8 lanes/edge (ushort4 x-load), acc[16]/thread.
//      4x fewer gather instructions, ~1.8x fewer VALU ops, same line traffic.

#define U_DIM 32
#define US 128

__device__ inline unsigned f2bf(float f) {          // RNE float->bf16 bits
    unsigned u = __float_as_uint(f);
    return (u + 0x7FFF + ((u >> 16) & 1)) >> 16;
}
__device__ inline float bfl(unsigned w) { return __uint_as_float(w << 16); }
__device__ inline float bfh(unsigned w) { return __uint_as_float(w & 0xFFFF0000u); }

__global__ void __launch_bounds__(256) xcvt_kernel(
        const float4* __restrict__ x4, ushort4* __restrict__ xb4, int n4) {
    int i = blockIdx.x * 256 + threadIdx.x;
    if (i < n4) {
        float4 v = x4[i];
        ushort4 r;
        r.x = (unsigned short)f2bf(v.x);
        r.y = (unsigned short)f2bf(v.y);
        r.z = (unsigned short)f2bf(v.z);
        r.w = (unsigned short)f2bf(v.w);
        xb4[i] = r;
    }
}

// =================== PRIMARY PATH ===================
#define C1_LOG 9
#define C1_NPB 512
#define C1_MAXK 256
#define C1_NBLK 256
#define FINE_LOG 7
#define FINE_NPB 128
#define KF_MAX 1024
#define SCAP 5120             // LDS-staged edges per fine bucket (mean 4082)

// Fine-granularity (128-node) histogram; also per-chunk coarse counts.
__global__ void __launch_bounds__(1024) c1_hist_kernel(
        const int* __restrict__ dst, int* __restrict__ ccount_f,
        int* __restrict__ cnt, int E, int KF, int K1, int EPB) {
    __shared__ int h[KF_MAX];
    for (int b = threadIdx.x; b < KF; b += 1024) h[b] = 0;
    __syncthreads();
    int base = blockIdx.x * EPB;
    int lim = min(EPB, E - base);
    for (int i = threadIdx.x; i < lim; i += 1024)
        atomicAdd(&h[dst[base + i] >> FINE_LOG], 1);
    __syncthreads();
    for (int b = threadIdx.x; b < KF; b += 1024) {
        int c = h[b];
        if (c) atomicAdd(&ccount_f[b], c);
    }
    for (int b = threadIdx.x; b < K1; b += 1024) {
        int c = 0;
        #pragma unroll
        for (int k = 0; k < 4; ++k) {
            int f = 4 * b + k;
            if (f < KF) c += h[f];
        }
        cnt[b * C1_NBLK + blockIdx.x] = c;
    }
}

// One scan over KF fine counts -> fbase; cbase derived; offsets[N]=E.
__global__ void __launch_bounds__(1024) c1_scan_kernel(
        const int* __restrict__ ccount_f, int* __restrict__ fbase,
        int* __restrict__ cbase, int* __restrict__ offsets,
        int KF, int K1, int N, int E) {
    __shared__ int sc[1024];
    int t = threadIdx.x;
    int v = (t < KF) ? ccount_f[t] : 0;
    sc[t] = v;
    __syncthreads();
    for (int off = 1; off < 1024; off <<= 1) {
        int w = (t >= off) ? sc[t - off] : 0;
        __syncthreads();
        sc[t] += w;
        __syncthreads();
    }
    if (t < KF) fbase[t] = sc[t] - v;
    __syncthreads();
    if (t < K1) {
        int f = 4 * t;
        cbase[t] = (f < KF) ? (sc[f] - ccount_f[f]) : E;
    }
    if (t == 0) { fbase[KF] = E; cbase[K1] = E; offsets[N] = E; }
}

__global__ void __launch_bounds__(C1_NBLK) c1_cbase_kernel(
        const int* __restrict__ cnt, const int* __restrict__ cbase,
        int* __restrict__ base_tab) {
    __shared__ int sc[C1_NBLK];
    int b = blockIdx.x;
    int t = threadIdx.x;
    int v = cnt[b * C1_NBLK + t];
    sc[t] = v;
    __syncthreads();
    for (int off = 1; off < C1_NBLK; off <<= 1) {
        int w = (t >= off) ? sc[t - off] : 0;
        __syncthreads();
        sc[t] += w;
        __syncthreads();
    }
    base_tab[b * C1_NBLK + t] = cbase[b] + sc[t] - v;
}

__global__ void __launch_bounds__(1024) c1_scatter_kernel(
        const int* __restrict__ dst, const int* __restrict__ src,
        const float4* __restrict__ sh, const int* __restrict__ base_tab,
        uint2* __restrict__ pay8A, int* __restrict__ packedA,
        int E, int K1, int EPB) {
    __shared__ int cur[C1_MAXK];
    for (int b = threadIdx.x; b < K1; b += 1024)
        cur[b] = base_tab[b * C1_NBLK + blockIdx.x];
    __syncthreads();
    int base = blockIdx.x * EPB;
    int lim = min(EPB, E - base);
    for (int i = threadIdx.x; i < lim; i += 1024) {
        int e = base + i;
        int d = dst[e];
        int b = d >> C1_LOG;
        int pos = atomicAdd(&cur[b], 1);
        float4 s4 = sh[e];
        pay8A[pos] = make_uint2(f2bf(s4.x) | (f2bf(s4.y) << 16),
                                f2bf(s4.z) | (f2bf(s4.w) << 16));
        packedA[pos] = ((d & (C1_NPB - 1)) << 21) | src[e];
    }
}

// One block per fine bucket: stream parent coarse range (L2-shared with 3
// sibling blocks), filter own sub-bucket, LDS-stage in sorted order, then
// DENSE coalesced write-out to B. Emits offsets[]. No scattered global writes.
__global__ void __launch_bounds__(512) c2_sort_kernel(
        const int* __restrict__ cbase, const int* __restrict__ fbase,
        int* __restrict__ offsets, const uint2* __restrict__ pay8A,
        const int* __restrict__ packedA, uint2* __restrict__ pay8B,
        int* __restrict__ packedB, int N) {
    __shared__ uint2 spay[SCAP];          // 40 KB
    __shared__ int   spk[SCAP];           // 20 KB
    __shared__ int   hh[FINE_NPB];
    __shared__ int   scur[FINE_NPB];
    int fb = blockIdx.x;
    int t = threadIdx.x;
    int parent = fb >> 2, sub = fb & 3;
    int cbeg = cbase[parent], cend = cbase[parent + 1];
    int fbeg = fbase[fb];
    int cnt = fbase[fb + 1] - fbeg;
    if (t < FINE_NPB) hh[t] = 0;
    __syncthreads();
    for (int i = cbeg + t; i < cend; i += 512) {
        int nc = (packedA[i] >> 21) & (C1_NPB - 1);
        if ((nc >> FINE_LOG) == sub)
            atomicAdd(&hh[nc & (FINE_NPB - 1)], 1);
    }
    __syncthreads();
    int v = (t < FINE_NPB) ? hh[t] : 0;
    if (t < FINE_NPB) hh[t] = v;
    __syncthreads();
    for (int off = 1; off < FINE_NPB; off <<= 1) {
        int w = (t < FINE_NPB && t >= off) ? hh[t - off] : 0;
        __syncthreads();
        if (t < FINE_NPB) hh[t] += w;
        __syncthreads();
    }
    if (t < FINE_NPB) {
        int excl = hh[t] - v;
        scur[t] = excl;
        int node = (fb << FINE_LOG) + t;
        if (node < N) offsets[node] = fbeg + excl;
    }
    __syncthreads();
    for (int i = cbeg + t; i < cend; i += 512) {
        int pk = packedA[i];
        int nc = (pk >> 21) & (C1_NPB - 1);
        if ((nc >> FINE_LOG) == sub) {
            int pos = atomicAdd(&scur[nc & (FINE_NPB - 1)], 1);
            uint2 p8 = pay8A[i];
            if (pos < SCAP) { spk[pos] = pk; spay[pos] = p8; }
            else { packedB[fbeg + pos] = pk; pay8B[fbeg + pos] = p8; }
        }
    }
    __syncthreads();
    int lim = min(cnt, SCAP);
    for (int i = t; i < lim; i += 512) {
        packedB[fbeg + i] = spk[i];
        pay8B[fbeg + i] = spay[i];
    }
}

// One block per node, 128 threads: t -> (u-quad ub=(t&7)*4, g=t>>3 owning a
// contiguous 1/16 of the node's edges). Per edge: 8 lanes, one ushort4 x-load
// each, 16 FMAs into acc[16] (static indices -> registers). Unroll-2 for MLP.
__global__ void __launch_bounds__(US) accum_kernel(
        const unsigned short* __restrict__ xb, const uint2* __restrict__ pay8,
        const int* __restrict__ packed, const int* __restrict__ offsets,
        float* __restrict__ out, int smask) {
    int n = blockIdx.x;
    int t = threadIdx.x;
    int ub = (t & 7) << 2;            // u base: 0,4,...,28
    int g = t >> 3;                   // 0..15 edge group
    int beg = offsets[n], end = offsets[n + 1];
    int len = end - beg;
    int q0 = beg + ((len * g) >> 4);
    int q1 = beg + ((len * (g + 1)) >> 4);
    float acc[16];
    #pragma unroll
    for (int j = 0; j < 16; ++j) acc[j] = 0.f;

    int i = q0;
    for (; i + 1 < q1; i += 2) {
        int pkA = packed[i], pkB = packed[i + 1];
        uint2 qA = pay8[i], qB = pay8[i + 1];
        ushort4 xA = *reinterpret_cast<const ushort4*>(
            &xb[(size_t)(pkA & smask) * U_DIM + ub]);
        ushort4 xB = *reinterpret_cast<const ushort4*>(
            &xb[(size_t)(pkB & smask) * U_DIM + ub]);
        float sA0 = bfl(qA.x), sA1 = bfh(qA.x), sA2 = bfl(qA.y), sA3 = bfh(qA.y);
        float sB0 = bfl(qB.x), sB1 = bfh(qB.x), sB2 = bfl(qB.y), sB3 = bfh(qB.y);
        float xA0 = bfl((unsigned)xA.x), xA1 = bfl((unsigned)xA.y);
        float xA2 = bfl((unsigned)xA.z), xA3 = bfl((unsigned)xA.w);
        float xB0 = bfl((unsigned)xB.x), xB1 = bfl((unsigned)xB.y);
        float xB2 = bfl((unsigned)xB.z), xB3 = bfl((unsigned)xB.w);
        acc[0]  += xA0 * sA0; acc[1]  += xA0 * sA1;
        acc[2]  += xA0 * sA2; acc[3]  += xA0 * sA3;
        acc[4]  += xA1 * sA0; acc[5]  += xA1 * sA1;
        acc[6]  += xA1 * sA2; acc[7]  += xA1 * sA3;
        acc[8]  += xA2 * sA0; acc[9]  += xA2 * sA1;
        acc[10] += xA2 * sA2; acc[11] += xA2 * sA3;
        acc[12] += xA3 * sA0; acc[13] += xA3 * sA1;
        acc[14] += xA3 * sA2; acc[15] += xA3 * sA3;
        acc[0]  += xB0 * sB0; acc[1]  += xB0 * sB1;
        acc[2]  += xB0 * sB2; acc[3]  += xB0 * sB3;
        acc[4]  += xB1 * sB0; acc[5]  += xB1 * sB1;
        acc[6]  += xB1 * sB2; acc[7]  += xB1 * sB3;
        acc[8]  += xB2 * sB0; acc[9]  += xB2 * sB1;
        acc[10] += xB2 * sB2; acc[11] += xB2 * sB3;
        acc[12] += xB3 * sB0; acc[13] += xB3 * sB1;
        acc[14] += xB3 * sB2; acc[15] += xB3 * sB3;
    }
    if (i < q1) {
        int pk = packed[i];
        uint2 qv = pay8[i];
        ushort4 xv = *reinterpret_cast<const ushort4*>(
            &xb[(size_t)(pk & smask) * U_DIM + ub]);
        float s0 = bfl(qv.x), s1 = bfh(qv.x), s2 = bfl(qv.y), s3 = bfh(qv.y);
        float x0 = bfl((unsigned)xv.x), x1 = bfl((unsigned)xv.y);
        float x2 = bfl((unsigned)xv.z), x3 = bfl((unsigned)xv.w);
        acc[0]  += x0 * s0; acc[1]  += x0 * s1; acc[2]  += x0 * s2; acc[3]  += x0 * s3;
        acc[4]  += x1 * s0; acc[5]  += x1 * s1; acc[6]  += x1 * s2; acc[7]  += x1 * s3;
        acc[8]  += x2 * s0; acc[9]  += x2 * s1; acc[10] += x2 * s2; acc[11] += x2 * s3;
        acc[12] += x3 * s0; acc[13] += x3 * s1; acc[14] += x3 * s2; acc[15] += x3 * s3;
    }
    // fold the 8 g-groups within each wave (g spans lane bits 3,4,5)
    #pragma unroll
    for (int j = 0; j < 16; ++j) {
        acc[j] += __shfl_xor(acc[j], 8);
        acc[j] += __shfl_xor(acc[j], 16);
        acc[j] += __shfl_xor(acc[j], 32);
    }
    __shared__ float red[128];
    int w = t >> 6, l = t & 63;
    if (w == 1 && l < 8) {
        #pragma unroll
        for (int j = 0; j < 16; ++j) red[l * 16 + j] = acc[j];
    }
    __syncthreads();
    if (w == 0 && l < 8) {
        size_t obase = (size_t)n * US + (size_t)ub * 4;
        #pragma unroll
        for (int jj = 0; jj < 4; ++jj) {
            float4 o = make_float4(acc[jj * 4 + 0] + red[l * 16 + jj * 4 + 0],
                                   acc[jj * 4 + 1] + red[l * 16 + jj * 4 + 1],
                                   acc[jj * 4 + 2] + red[l * 16 + jj * 4 + 2],
                                   acc[jj * 4 + 3] + red[l * 16 + jj * 4 + 3]);
            *reinterpret_cast<float4*>(&out[obase + jj * 4]) = o;
        }
    }
}

// =================== TIER-2: proven R7 path ===================
#define LOG_NPBK 7
#define NPBK 128
#define MAXK 1024
#define NBLK 256
#define CAP 5120
#define SPILL_E 1000000

__global__ void __launch_bounds__(1024) coarse_hist_kernel(
        const int* __restrict__ dst, int* __restrict__ ccount,
        int* __restrict__ cnt, int E, int K, int EPB) {
    __shared__ int h[MAXK];
    for (int b = threadIdx.x; b < K; b += 1024) h[b] = 0;
    __syncthreads();
    int base = blockIdx.x * EPB;
    int lim = min(EPB, E - base);
    for (int i = threadIdx.x; i < lim; i += 1024)
        atomicAdd(&h[dst[base + i] >> LOG_NPBK], 1);
    __syncthreads();
    for (int b = threadIdx.x; b < K; b += 1024) {
        int c = h[b];
        cnt[b * NBLK + blockIdx.x] = c;
        if (c) atomicAdd(&ccount[b], c);
    }
}

__global__ void __launch_bounds__(1024) coarse_scan_kernel(
        const int* __restrict__ ccount, int* __restrict__ cbase,
        int* __restrict__ offsets, int* __restrict__ spill_cursor,
        int K, int N, int E) {
    __shared__ int sc[1024];
    int t = threadIdx.x;
    int v = (t < K) ? ccount[t] : 0;
    sc[t] = v;
    __syncthreads();
    for (int off = 1; off < 1024; off <<= 1) {
        int w = (t >= off) ? sc[t - off] : 0;
        __syncthreads();
        sc[t] += w;
        __syncthreads();
    }
    if (t < K) cbase[t] = sc[t] - v;
    if (t == 0) { cbase[K] = E; offsets[N] = E; *spill_cursor = 0; }
}

__global__ void __launch_bounds__(NBLK) chunk_base_kernel(
        const int* __restrict__ cnt, const int* __restrict__ cbase,
        int* __restrict__ base_tab) {
    __shared__ int sc[NBLK];
    int b = blockIdx.x;
    int t = threadIdx.x;
    int v = cnt[b * NBLK + t];
    sc[t] = v;
    __syncthreads();
    for (int off = 1; off < NBLK; off <<= 1) {
        int w = (t >= off) ? sc[t - off] : 0;
        __syncthreads();
        sc[t] += w;
        __syncthreads();
    }
    base_tab[b * NBLK + t] = cbase[b] + sc[t] - v;
}

__global__ void __launch_bounds__(1024) coarse_scatter_kernel(
        const int* __restrict__ dst, const int* __restrict__ src,
        const float4* __restrict__ sh, const int* __restrict__ base_tab,
        uint2* __restrict__ pay8, int* __restrict__ packed,
        int E, int K, int EPB) {
    __shared__ int cur[MAXK];
    for (int b = threadIdx.x; b < K; b += 1024)
        cur[b] = base_tab[b * NBLK + blockIdx.x];
    __syncthreads();
    int base = blockIdx.x * EPB;
    int lim = min(EPB, E - base);
    for (int i = threadIdx.x; i < lim; i += 1024) {
        int e = base + i;
        int d = dst[e];
        int b = d >> LOG_NPBK;
        int pos = atomicAdd(&cur[b], 1);
        float4 s4 = sh[e];
        pay8[pos] = make_uint2(f2bf(s4.x) | (f2bf(s4.y) << 16),
                               f2bf(s4.z) | (f2bf(s4.w) << 16));
        packed[pos] = ((d & (NPBK - 1)) << 24) | src[e];
    }
}

__global__ void __launch_bounds__(512) fine_sort_kernel(
        const int* __restrict__ cbase, int* __restrict__ offsets,
        uint2* __restrict__ pay8, int* __restrict__ packed,
        uint2* __restrict__ spill_pay, int* __restrict__ spill_pk,
        int* __restrict__ spill_cursor, int N) {
    __shared__ uint2 spay[CAP];
    __shared__ int   spk[CAP];
    __shared__ int   cnt_[NPBK];
    __shared__ int   sc[NPBK];
    __shared__ int   sbase_s;
    int b = blockIdx.x;
    int t = threadIdx.x;
    int cbeg = cbase[b], cend = cbase[b + 1];
    int cnt = cend - cbeg;
    if (t == 0) sbase_s = (cnt > CAP) ? atomicAdd(spill_cursor, cnt - CAP) : 0;
    if (t < NPBK) cnt_[t] = 0;
    __syncthreads();
    for (int i = t; i < cnt; i += 512) {
        int pk = packed[cbeg + i];
        uint2 p8 = pay8[cbeg + i];
        atomicAdd(&cnt_[(pk >> 24) & (NPBK - 1)], 1);
        if (i < CAP) { spk[i] = pk; spay[i] = p8; }
        else {
            int sp = sbase_s + (i - CAP);
            if (sp < SPILL_E) { spill_pk[sp] = pk; spill_pay[sp] = p8; }
        }
    }
    __syncthreads();
    int v = (t < NPBK) ? cnt_[t] : 0;
    if (t < NPBK) sc[t] = v;
    __syncthreads();
    for (int off = 1; off < NPBK; off <<= 1) {
        int w = (t < NPBK && t >= off) ? sc[t - off] : 0;
        __syncthreads();
        if (t < NPBK) sc[t] += w;
        __syncthreads();
    }
    if (t < NPBK) {
        int ex = sc[t] - v;
        int node = (b << LOG_NPBK) + t;
        if (node <= N) offsets[node] = cbeg + ex;
        cnt_[t] = ex;
    }
    __syncthreads();
    for (int i = t; i < cnt; i += 512) {
        int pk; uint2 p8;
        bool ok = true;
        if (i < CAP) { pk = spk[i]; p8 = spay[i]; }
        else {
            int sp = sbase_s + (i - CAP);
            ok = (sp < SPILL_E);
            if (ok) { pk = spill_pk[sp]; p8 = spill_pay[sp]; }
        }
        if (ok) {
            int pos = cbeg + atomicAdd(&cnt_[(pk >> 24) & (NPBK - 1)], 1);
            packed[pos] = pk;
            pay8[pos] = p8;
        }
    }
}

// --- Fallback tiers 3/4 ---
constexpr int SCAN_BLOCK = 256;
constexpr int SCAN_ITEMS = 8;
constexpr int SCAN_CHUNK = SCAN_BLOCK * SCAN_ITEMS;

__global__ void __launch_bounds__(256) hist_kernel(
        const int* __restrict__ dst, int* __restrict__ counts, int E) {
    int e = blockIdx.x * blockDim.x + threadIdx.x;
    if (e < E) atomicAdd(&counts[dst[e]], 1);
}
__global__ void __launch_bounds__(SCAN_BLOCK) block_sum_kernel(
        const int* __restrict__ counts, int* __restrict__ bsums, int N) {
    __shared__ int sdata[SCAN_BLOCK];
    int base = blockIdx.x * SCAN_CHUNK;
    int sum = 0;
    for (int j = 0; j < SCAN_ITEMS; ++j) {
        int idx = base + j * SCAN_BLOCK + threadIdx.x;
        if (idx < N) sum += counts[idx];
    }
    sdata[threadIdx.x] = sum;
    __syncthreads();
    for (int off = SCAN_BLOCK / 2; off > 0; off >>= 1) {
        if (threadIdx.x < off) sdata[threadIdx.x] += sdata[threadIdx.x + off];
        __syncthreads();
    }
    if (threadIdx.x == 0) bsums[blockIdx.x] = sdata[0];
}
__global__ void scan_bsums_kernel(int* __restrict__ bsums, int nb) {
    if (threadIdx.x == 0 && blockIdx.x == 0) {
        int acc = 0;
        for (int i = 0; i < nb; ++i) { int v = bsums[i]; bsums[i] = acc; acc += v; }
    }
}
__global__ void __launch_bounds__(SCAN_BLOCK) scan_final_kernel(
        const int* __restrict__ counts, const int* __restrict__ bsums,
        int* __restrict__ offsets, int* __restrict__ cursors, int N, int E) {
    __shared__ int sdata[SCAN_BLOCK];
    int base = blockIdx.x * SCAN_CHUNK + threadIdx.x * SCAN_ITEMS;
    int local[SCAN_ITEMS];
    int tsum = 0;
    for (int j = 0; j < SCAN_ITEMS; ++j) {
        int idx = base + j;
        int v = (idx < N) ? counts[idx] : 0;
        local[j] = tsum;
        tsum += v;
    }
    sdata[threadIdx.x] = tsum;
    __syncthreads();
    for (int off = 1; off < SCAN_BLOCK; off <<= 1) {
        int v = (threadIdx.x >= off) ? sdata[threadIdx.x - off] : 0;
        __syncthreads();
        sdata[threadIdx.x] += v;
        __syncthreads();
    }
    int excl = sdata[threadIdx.x] - tsum + bsums[blockIdx.x];
    for (int j = 0; j < SCAN_ITEMS; ++j) {
        int idx = base + j;
        if (idx < N) { int o = excl + local[j]; offsets[idx] = o; cursors[idx] = o; }
    }
    if (blockIdx.x == 0 && threadIdx.x == 0) offsets[N] = E;
}
__global__ void __launch_bounds__(256) scatter_ids_kernel(
        const int* __restrict__ dst, int* __restrict__ cursors,
        int* __restrict__ eids, int E) {
    int e = blockIdx.x * blockDim.x + threadIdx.x;
    if (e < E) { int pos = atomicAdd(&cursors[dst[e]], 1); eids[pos] = e; }
}
__global__ void __launch_bounds__(US) accum_ids_kernel(
        const float* __restrict__ x, const float* __restrict__ sh,
        const int* __restrict__ src, const int* __restrict__ offsets,
        const int* __restrict__ eids, float* __restrict__ out) {
    int n = blockIdx.x;
    int t = threadIdx.x;
    int u = t >> 2, s = t & 3;
    int beg = offsets[n], end = offsets[n + 1];
    float acc = 0.f;
    for (int i = beg; i < end; ++i) {
        int e = eids[i];
        acc += x[src[e] * U_DIM + u] * sh[e * 4 + s];
    }
    out[(size_t)n * US + t] = acc;
}
__global__ void __launch_bounds__(US) atomic_kernel(
        const float* __restrict__ x, const float* __restrict__ sh,
        const int* __restrict__ src, const int* __restrict__ dst,
        float* __restrict__ out, int E) {
    int e = blockIdx.x;
    int t = threadIdx.x;
    float v = x[src[e] * U_DIM + (t >> 2)] * sh[e * 4 + (t & 3)];
    atomicAdd(&out[(size_t)dst[e] * US + t], v);
}

extern "C" void kernel_launch(void* const* d_in, const int* in_sizes, int n_in,
                              void* d_out, int out_size, void* d_ws, size_t ws_size,
                              hipStream_t stream) {
    const float* x  = (const float*)d_in[0];
    const float* sh = (const float*)d_in[1];
    const int* src  = (const int*)d_in[2];
    const int* dst  = (const int*)d_in[3];
    float* out = (float*)d_out;

    const int E = in_sizes[2];
    const int N = in_sizes[0] / U_DIM;
    const int xn4 = in_sizes[0] / 4;
    const int egrid = (E + 255) / 256;
    const int nb = (N + SCAN_CHUNK - 1) / SCAN_CHUNK;

    const int K1 = (N + C1_NPB - 1) >> C1_LOG;
    const int KF = (N + FINE_NPB - 1) >> FINE_LOG;
    const int EPB1 = (E + C1_NBLK - 1) / C1_NBLK;
    size_t need_main = (size_t)E * 24 + (size_t)in_sizes[0] * 2 +
                       (size_t)(N + 1 + 2 * KF + 2 + K1 + 1 +
                                2 * K1 * C1_NBLK) * 4;

    const int K = (N + NPBK - 1) >> LOG_NPBK;
    const int EPB = (E + NBLK - 1) / NBLK;
    size_t need_r7 = (size_t)E * 12 + (size_t)SPILL_E * 12 + (size_t)(N + 1) * 4 +
                     (size_t)(2 * K + 2) * 4 + (size_t)(2 * K * NBLK) * 4 +
                     (size_t)in_sizes[0] * 2;
    size_t need_ids = (size_t)E * 4 + (size_t)(3 * N + 1 + nb) * 4;

    if (K1 <= C1_MAXK && KF <= KF_MAX && N <= (1 << 21) &&
        (in_sizes[0] % 4 == 0) && ws_size >= need_main) {
        uint2* pay8A   = (uint2*)d_ws;
        uint2* pay8B   = pay8A + E;
        int* packedA   = (int*)(pay8B + E);
        int* packedB   = packedA + E;
        unsigned short* xb = (unsigned short*)(packedB + E);
        int* offsets   = (int*)(xb + in_sizes[0]);
        int* ccount_f  = offsets + N + 1;
        int* fbase     = ccount_f + KF;
        int* cbase     = fbase + KF + 1;
        int* cnt       = cbase + K1 + 1;
        int* base_tab  = cnt + K1 * C1_NBLK;

        hipMemsetAsync(ccount_f, 0, sizeof(int) * (size_t)KF, stream);
        xcvt_kernel<<<(xn4 + 255) / 256, 256, 0, stream>>>(
            (const float4*)x, (ushort4*)xb, xn4);
        c1_hist_kernel<<<C1_NBLK, 1024, 0, stream>>>(dst, ccount_f, cnt,
                                                     E, KF, K1, EPB1);
        c1_scan_kernel<<<1, 1024, 0, stream>>>(ccount_f, fbase, cbase, offsets,
                                               KF, K1, N, E);
        c1_cbase_kernel<<<K1, C1_NBLK, 0, stream>>>(cnt, cbase, base_tab);
        c1_scatter_kernel<<<C1_NBLK, 1024, 0, stream>>>(dst, src, (const float4*)sh,
                                                        base_tab, pay8A, packedA,
                                                        E, K1, EPB1);
        c2_sort_kernel<<<KF, 512, 0, stream>>>(cbase, fbase, offsets,
                                               pay8A, packedA, pay8B, packedB, N);
        accum_kernel<<<N, US, 0, stream>>>(xb, pay8B, packedB, offsets, out,
                                           0x1FFFFF);
    } else if (K <= MAXK && (in_sizes[0] % 4 == 0) && ws_size >= need_r7) {
        uint2* pay8      = (uint2*)d_ws;
        uint2* spill_pay = pay8 + E;
        int* packed      = (int*)(spill_pay + SPILL_E);
        int* spill_pk    = packed + E;
        int* offsets     = spill_pk + SPILL_E;
        int* ccount      = offsets + N + 1;
        int* cbase       = ccount + K;
        int* cnt         = cbase + K + 1;
        int* base_tab    = cnt + K * NBLK;
        int* spill_cur   = base_tab + K * NBLK;
        unsigned short* xb = (unsigned short*)(spill_cur + 1);

        hipMemsetAsync(ccount, 0, sizeof(int) * (size_t)K, stream);
        xcvt_kernel<<<(xn4 + 255) / 256, 256, 0, stream>>>(
            (const float4*)x, (ushort4*)xb, xn4);
        coarse_hist_kernel<<<NBLK, 1024, 0, stream>>>(dst, ccount, cnt, E, K, EPB);
        coarse_scan_kernel<<<1, 1024, 0, stream>>>(ccount, cbase, offsets,
                                                   spill_cur, K, N, E);
        chunk_base_kernel<<<K, NBLK, 0, stream>>>(cnt, cbase, base_tab);
        coarse_scatter_kernel<<<NBLK, 1024, 0, stream>>>(dst, src, (const float4*)sh,
                                                         base_tab, pay8, packed,
                                                         E, K, EPB);
        fine_sort_kernel<<<K, 512, 0, stream>>>(cbase, offsets, pay8, packed,
                                                spill_pay, spill_pk, spill_cur, N);
        accum_kernel<<<N, US, 0, stream>>>(xb, pay8, packed, offsets, out,
                                           0xFFFFFF);
    } else if (ws_size >= need_ids) {
        int* eids    = (int*)d_ws;
        int* counts  = eids + E;
        int* offsets = counts + N;
        int* cursors = offsets + N + 1;
        int* bsums   = cursors + N;

        hipMemsetAsync(counts, 0, sizeof(int) * (size_t)N, stream);
        hist_kernel<<<egrid, 256, 0, stream>>>(dst, counts, E);
        block_sum_kernel<<<nb, SCAN_BLOCK, 0, stream>>>(counts, bsums, N);
        scan_bsums_kernel<<<1, 64, 0, stream>>>(bsums, nb);
        scan_final_kernel<<<nb, SCAN_BLOCK, 0, stream>>>(counts, bsums, offsets, cursors, N, E);
        scatter_ids_kernel<<<egrid, 256, 0, stream>>>(dst, cursors, eids, E);
        accum_ids_kernel<<<N, US, 0, stream>>>(x, sh, src, offsets, eids, out);
    } else {
        hipMemsetAsync(out, 0, sizeof(float) * (size_t)out_size, stream);
        atomic_kernel<<<E, US, 0, stream>>>(x, sh, src, dst, out, E);
    }
}

// Round 13
// 251.829 us; speedup vs baseline: 1.1218x; 1.1218x over previous
//
#include <hip/hip_runtime.h>

// out[n, u*4+s] = sum_{e: dst[e]==n} x[src[e], u] * sh[e, s]
// N=100000, U=32, S=4, E=3200000.
//
// Ledger of lessons:
//  R2: bulk LDS float atomics = ~1 lane/cycle serial floor -> register accum.
//  R4/R5/R7: scattered writes into >~400 streams/block = 4.3x HBM write amp.
//  R8: few deep-serial blocks (17% occ) lose to 100k shallow blocks.
//  R9: xb gather is L2-miss/L3-served (6.4MB > 4MB per-XCD L2, uniform).
//  R10: NT loads on broadcast/shared streams re-fetch lines (FETCH +11MB).
//  R11: contiguous per-lane ranges + 4 independent gathers in flight: 99us.
//  R12: 16-way edge split + acc[16] = reduction (48 shfl, 1.2M bank-conflict)
//       swamps ~1-iter loops. 4-way split is the sweet spot at ~32 edges/node.
// R13: accum reverted to R11 exactly; c2_sort gets XCD-swizzled block mapping
//      so the 4 sibling blocks of one parent share one L2 (1x parent read).

#define U_DIM 32
#define US 128

__device__ inline unsigned f2bf(float f) {          // RNE float->bf16 bits
    unsigned u = __float_as_uint(f);
    return (u + 0x7FFF + ((u >> 16) & 1)) >> 16;
}
__device__ inline float bfl(unsigned w) { return __uint_as_float(w << 16); }
__device__ inline float bfh(unsigned w) { return __uint_as_float(w & 0xFFFF0000u); }

__global__ void __launch_bounds__(256) xcvt_kernel(
        const float4* __restrict__ x4, ushort4* __restrict__ xb4, int n4) {
    int i = blockIdx.x * 256 + threadIdx.x;
    if (i < n4) {
        float4 v = x4[i];
        ushort4 r;
        r.x = (unsigned short)f2bf(v.x);
        r.y = (unsigned short)f2bf(v.y);
        r.z = (unsigned short)f2bf(v.z);
        r.w = (unsigned short)f2bf(v.w);
        xb4[i] = r;
    }
}

// =================== PRIMARY PATH ===================
#define C1_LOG 9
#define C1_NPB 512
#define C1_MAXK 256
#define C1_NBLK 256
#define FINE_LOG 7
#define FINE_NPB 128
#define KF_MAX 1024
#define SCAP 5120             // LDS-staged edges per fine bucket (mean 4082)

// Fine-granularity (128-node) histogram; also per-chunk coarse counts.
__global__ void __launch_bounds__(1024) c1_hist_kernel(
        const int* __restrict__ dst, int* __restrict__ ccount_f,
        int* __restrict__ cnt, int E, int KF, int K1, int EPB) {
    __shared__ int h[KF_MAX];
    for (int b = threadIdx.x; b < KF; b += 1024) h[b] = 0;
    __syncthreads();
    int base = blockIdx.x * EPB;
    int lim = min(EPB, E - base);
    for (int i = threadIdx.x; i < lim; i += 1024)
        atomicAdd(&h[dst[base + i] >> FINE_LOG], 1);
    __syncthreads();
    for (int b = threadIdx.x; b < KF; b += 1024) {
        int c = h[b];
        if (c) atomicAdd(&ccount_f[b], c);
    }
    for (int b = threadIdx.x; b < K1; b += 1024) {
        int c = 0;
        #pragma unroll
        for (int k = 0; k < 4; ++k) {
            int f = 4 * b + k;
            if (f < KF) c += h[f];
        }
        cnt[b * C1_NBLK + blockIdx.x] = c;
    }
}

// One scan over KF fine counts -> fbase; cbase derived; offsets[N]=E.
__global__ void __launch_bounds__(1024) c1_scan_kernel(
        const int* __restrict__ ccount_f, int* __restrict__ fbase,
        int* __restrict__ cbase, int* __restrict__ offsets,
        int KF, int K1, int N, int E) {
    __shared__ int sc[1024];
    int t = threadIdx.x;
    int v = (t < KF) ? ccount_f[t] : 0;
    sc[t] = v;
    __syncthreads();
    for (int off = 1; off < 1024; off <<= 1) {
        int w = (t >= off) ? sc[t - off] : 0;
        __syncthreads();
        sc[t] += w;
        __syncthreads();
    }
    if (t < KF) fbase[t] = sc[t] - v;
    __syncthreads();
    if (t < K1) {
        int f = 4 * t;
        cbase[t] = (f < KF) ? (sc[f] - ccount_f[f]) : E;
    }
    if (t == 0) { fbase[KF] = E; cbase[K1] = E; offsets[N] = E; }
}

__global__ void __launch_bounds__(C1_NBLK) c1_cbase_kernel(
        const int* __restrict__ cnt, const int* __restrict__ cbase,
        int* __restrict__ base_tab) {
    __shared__ int sc[C1_NBLK];
    int b = blockIdx.x;
    int t = threadIdx.x;
    int v = cnt[b * C1_NBLK + t];
    sc[t] = v;
    __syncthreads();
    for (int off = 1; off < C1_NBLK; off <<= 1) {
        int w = (t >= off) ? sc[t - off] : 0;
        __syncthreads();
        sc[t] += w;
        __syncthreads();
    }
    base_tab[b * C1_NBLK + t] = cbase[b] + sc[t] - v;
}

__global__ void __launch_bounds__(1024) c1_scatter_kernel(
        const int* __restrict__ dst, const int* __restrict__ src,
        const float4* __restrict__ sh, const int* __restrict__ base_tab,
        uint2* __restrict__ pay8A, int* __restrict__ packedA,
        int E, int K1, int EPB) {
    __shared__ int cur[C1_MAXK];
    for (int b = threadIdx.x; b < K1; b += 1024)
        cur[b] = base_tab[b * C1_NBLK + blockIdx.x];
    __syncthreads();
    int base = blockIdx.x * EPB;
    int lim = min(EPB, E - base);
    for (int i = threadIdx.x; i < lim; i += 1024) {
        int e = base + i;
        int d = dst[e];
        int b = d >> C1_LOG;
        int pos = atomicAdd(&cur[b], 1);
        float4 s4 = sh[e];
        pay8A[pos] = make_uint2(f2bf(s4.x) | (f2bf(s4.y) << 16),
                                f2bf(s4.z) | (f2bf(s4.w) << 16));
        packedA[pos] = ((d & (C1_NPB - 1)) << 21) | src[e];
    }
}

// One block per fine bucket, XCD-SWIZZLED so the 4 siblings of one parent
// map to the same blockIdx%8 (same XCD L2): parent range fetched once, not 4x.
// Stream parent range, filter own sub-bucket, LDS-stage sorted, dense write.
__global__ void __launch_bounds__(512) c2_sort_kernel(
        const int* __restrict__ cbase, const int* __restrict__ fbase,
        int* __restrict__ offsets, const uint2* __restrict__ pay8A,
        const int* __restrict__ packedA, uint2* __restrict__ pay8B,
        int* __restrict__ packedB, int N, int K1, int KF) {
    __shared__ uint2 spay[SCAP];          // 40 KB
    __shared__ int   spk[SCAP];           // 20 KB
    __shared__ int   hh[FINE_NPB];
    __shared__ int   scur[FINE_NPB];
    // swizzled mapping: b = slot + 8*(prow*4 + k); parent = prow*8 + slot
    int b = blockIdx.x;
    int slot = b & 7;
    int idx = b >> 3;
    int k = idx & 3;
    int prow = idx >> 2;
    int parent = prow * 8 + slot;
    if (parent >= K1) return;
    int fb = parent * 4 + k;
    if (fb >= KF) return;
    int t = threadIdx.x;
    int cbeg = cbase[parent], cend = cbase[parent + 1];
    int fbeg = fbase[fb];
    int cnt = fbase[fb + 1] - fbeg;
    if (t < FINE_NPB) hh[t] = 0;
    __syncthreads();
    for (int i = cbeg + t; i < cend; i += 512) {
        int nc = (packedA[i] >> 21) & (C1_NPB - 1);
        if ((nc >> FINE_LOG) == k)
            atomicAdd(&hh[nc & (FINE_NPB - 1)], 1);
    }
    __syncthreads();
    int v = (t < FINE_NPB) ? hh[t] : 0;
    if (t < FINE_NPB) hh[t] = v;
    __syncthreads();
    for (int off = 1; off < FINE_NPB; off <<= 1) {
        int w = (t < FINE_NPB && t >= off) ? hh[t - off] : 0;
        __syncthreads();
        if (t < FINE_NPB) hh[t] += w;
        __syncthreads();
    }
    if (t < FINE_NPB) {
        int excl = hh[t] - v;
        scur[t] = excl;
        int node = (fb << FINE_LOG) + t;
        if (node < N) offsets[node] = fbeg + excl;
    }
    __syncthreads();
    for (int i = cbeg + t; i < cend; i += 512) {
        int pk = packedA[i];
        int nc = (pk >> 21) & (C1_NPB - 1);
        if ((nc >> FINE_LOG) == k) {
            int pos = atomicAdd(&scur[nc & (FINE_NPB - 1)], 1);
            uint2 p8 = pay8A[i];
            if (pos < SCAP) { spk[pos] = pk; spay[pos] = p8; }
            else { packedB[fbeg + pos] = pk; pay8B[fbeg + pos] = p8; }
        }
    }
    __syncthreads();
    int lim = min(cnt, SCAP);
    for (int i = t; i < lim; i += 512) {
        packedB[fbeg + i] = spk[i];
        pay8B[fbeg + i] = spay[i];
    }
}

// One block per node, 128 threads: u = t&31, g = t>>5 owns a CONTIGUOUS
// quarter of the node's edges. Unroll-4: 4 independent xb gathers in flight.
// (R11-proven structure; R12's 16-way split regressed.)
__global__ void __launch_bounds__(US) accum_kernel(
        const unsigned short* __restrict__ xb, const uint2* __restrict__ pay8,
        const int* __restrict__ packed, const int* __restrict__ offsets,
        float* __restrict__ out, int smask) {
    int n = blockIdx.x;
    int t = threadIdx.x;
    int u = t & 31;
    int g = t >> 5;
    int beg = offsets[n], end = offsets[n + 1];
    int len = end - beg;
    int q0 = beg + ((len * g) >> 2);
    int q1 = beg + ((len * (g + 1)) >> 2);
    float a0 = 0.f, a1 = 0.f, a2 = 0.f, a3 = 0.f;
    int i = q0;
    for (; i + 3 < q1; i += 4) {
        int pk0 = packed[i], pk1 = packed[i + 1];
        int pk2 = packed[i + 2], pk3 = packed[i + 3];
        uint2 qv0 = pay8[i], qv1 = pay8[i + 1];
        uint2 qv2 = pay8[i + 2], qv3 = pay8[i + 3];
        float x0 = bfl((unsigned)xb[(size_t)(pk0 & smask) * U_DIM + u]);
        float x1 = bfl((unsigned)xb[(size_t)(pk1 & smask) * U_DIM + u]);
        float x2 = bfl((unsigned)xb[(size_t)(pk2 & smask) * U_DIM + u]);
        float x3 = bfl((unsigned)xb[(size_t)(pk3 & smask) * U_DIM + u]);
        a0 += x0 * bfl(qv0.x); a1 += x0 * bfh(qv0.x);
        a2 += x0 * bfl(qv0.y); a3 += x0 * bfh(qv0.y);
        a0 += x1 * bfl(qv1.x); a1 += x1 * bfh(qv1.x);
        a2 += x1 * bfl(qv1.y); a3 += x1 * bfh(qv1.y);
        a0 += x2 * bfl(qv2.x); a1 += x2 * bfh(qv2.x);
        a2 += x2 * bfl(qv2.y); a3 += x2 * bfh(qv2.y);
        a0 += x3 * bfl(qv3.x); a1 += x3 * bfh(qv3.x);
        a2 += x3 * bfl(qv3.y); a3 += x3 * bfh(qv3.y);
    }
    for (; i < q1; ++i) {
        int pk = packed[i];
        uint2 qv = pay8[i];
        float xv = bfl((unsigned)xb[(size_t)(pk & smask) * U_DIM + u]);
        a0 += xv * bfl(qv.x); a1 += xv * bfh(qv.x);
        a2 += xv * bfl(qv.y); a3 += xv * bfh(qv.y);
    }
    a0 += __shfl_xor(a0, 32);
    a1 += __shfl_xor(a1, 32);
    a2 += __shfl_xor(a2, 32);
    a3 += __shfl_xor(a3, 32);
    __shared__ float red[US];
    int w = t >> 6, l = t & 63;
    if (w == 1 && l < 32) {
        red[l * 4 + 0] = a0; red[l * 4 + 1] = a1;
        red[l * 4 + 2] = a2; red[l * 4 + 3] = a3;
    }
    __syncthreads();
    if (w == 0 && l < 32) {
        float4 o = make_float4(a0 + red[l * 4 + 0], a1 + red[l * 4 + 1],
                               a2 + red[l * 4 + 2], a3 + red[l * 4 + 3]);
        *reinterpret_cast<float4*>(&out[(size_t)n * US + l * 4]) = o;
    }
}

// =================== TIER-2: proven R7 path ===================
#define LOG_NPBK 7
#define NPBK 128
#define MAXK 1024
#define NBLK 256
#define CAP 5120
#define SPILL_E 1000000

__global__ void __launch_bounds__(1024) coarse_hist_kernel(
        const int* __restrict__ dst, int* __restrict__ ccount,
        int* __restrict__ cnt, int E, int K, int EPB) {
    __shared__ int h[MAXK];
    for (int b = threadIdx.x; b < K; b += 1024) h[b] = 0;
    __syncthreads();
    int base = blockIdx.x * EPB;
    int lim = min(EPB, E - base);
    for (int i = threadIdx.x; i < lim; i += 1024)
        atomicAdd(&h[dst[base + i] >> LOG_NPBK], 1);
    __syncthreads();
    for (int b = threadIdx.x; b < K; b += 1024) {
        int c = h[b];
        cnt[b * NBLK + blockIdx.x] = c;
        if (c) atomicAdd(&ccount[b], c);
    }
}

__global__ void __launch_bounds__(1024) coarse_scan_kernel(
        const int* __restrict__ ccount, int* __restrict__ cbase,
        int* __restrict__ offsets, int* __restrict__ spill_cursor,
        int K, int N, int E) {
    __shared__ int sc[1024];
    int t = threadIdx.x;
    int v = (t < K) ? ccount[t] : 0;
    sc[t] = v;
    __syncthreads();
    for (int off = 1; off < 1024; off <<= 1) {
        int w = (t >= off) ? sc[t - off] : 0;
        __syncthreads();
        sc[t] += w;
        __syncthreads();
    }
    if (t < K) cbase[t] = sc[t] - v;
    if (t == 0) { cbase[K] = E; offsets[N] = E; *spill_cursor = 0; }
}

__global__ void __launch_bounds__(NBLK) chunk_base_kernel(
        const int* __restrict__ cnt, const int* __restrict__ cbase,
        int* __restrict__ base_tab) {
    __shared__ int sc[NBLK];
    int b = blockIdx.x;
    int t = threadIdx.x;
    int v = cnt[b * NBLK + t];
    sc[t] = v;
    __syncthreads();
    for (int off = 1; off < NBLK; off <<= 1) {
        int w = (t >= off) ? sc[t - off] : 0;
        __syncthreads();
        sc[t] += w;
        __syncthreads();
    }
    base_tab[b * NBLK + t] = cbase[b] + sc[t] - v;
}

__global__ void __launch_bounds__(1024) coarse_scatter_kernel(
        const int* __restrict__ dst, const int* __restrict__ src,
        const float4* __restrict__ sh, const int* __restrict__ base_tab,
        uint2* __restrict__ pay8, int* __restrict__ packed,
        int E, int K, int EPB) {
    __shared__ int cur[MAXK];
    for (int b = threadIdx.x; b < K; b += 1024)
        cur[b] = base_tab[b * NBLK + blockIdx.x];
    __syncthreads();
    int base = blockIdx.x * EPB;
    int lim = min(EPB, E - base);
    for (int i = threadIdx.x; i < lim; i += 1024) {
        int e = base + i;
        int d = dst[e];
        int b = d >> LOG_NPBK;
        int pos = atomicAdd(&cur[b], 1);
        float4 s4 = sh[e];
        pay8[pos] = make_uint2(f2bf(s4.x) | (f2bf(s4.y) << 16),
                               f2bf(s4.z) | (f2bf(s4.w) << 16));
        packed[pos] = ((d & (NPBK - 1)) << 24) | src[e];
    }
}

__global__ void __launch_bounds__(512) fine_sort_kernel(
        const int* __restrict__ cbase, int* __restrict__ offsets,
        uint2* __restrict__ pay8, int* __restrict__ packed,
        uint2* __restrict__ spill_pay, int* __restrict__ spill_pk,
        int* __restrict__ spill_cursor, int N) {
    __shared__ uint2 spay[CAP];
    __shared__ int   spk[CAP];
    __shared__ int   cnt_[NPBK];
    __shared__ int   sc[NPBK];
    __shared__ int   sbase_s;
    int b = blockIdx.x;
    int t = threadIdx.x;
    int cbeg = cbase[b], cend = cbase[b + 1];
    int cnt = cend - cbeg;
    if (t == 0) sbase_s = (cnt > CAP) ? atomicAdd(spill_cursor, cnt - CAP) : 0;
    if (t < NPBK) cnt_[t] = 0;
    __syncthreads();
    for (int i = t; i < cnt; i += 512) {
        int pk = packed[cbeg + i];
        uint2 p8 = pay8[cbeg + i];
        atomicAdd(&cnt_[(pk >> 24) & (NPBK - 1)], 1);
        if (i < CAP) { spk[i] = pk; spay[i] = p8; }
        else {
            int sp = sbase_s + (i - CAP);
            if (sp < SPILL_E) { spill_pk[sp] = pk; spill_pay[sp] = p8; }
        }
    }
    __syncthreads();
    int v = (t < NPBK) ? cnt_[t] : 0;
    if (t < NPBK) sc[t] = v;
    __syncthreads();
    for (int off = 1; off < NPBK; off <<= 1) {
        int w = (t < NPBK && t >= off) ? sc[t - off] : 0;
        __syncthreads();
        if (t < NPBK) sc[t] += w;
        __syncthreads();
    }
    if (t < NPBK) {
        int ex = sc[t] - v;
        int node = (b << LOG_NPBK) + t;
        if (node <= N) offsets[node] = cbeg + ex;
        cnt_[t] = ex;
    }
    __syncthreads();
    for (int i = t; i < cnt; i += 512) {
        int pk; uint2 p8;
        bool ok = true;
        if (i < CAP) { pk = spk[i]; p8 = spay[i]; }
        else {
            int sp = sbase_s + (i - CAP);
            ok = (sp < SPILL_E);
            if (ok) { pk = spill_pk[sp]; p8 = spill_pay[sp]; }
        }
        if (ok) {
            int pos = cbeg + atomicAdd(&cnt_[(pk >> 24) & (NPBK - 1)], 1);
            packed[pos] = pk;
            pay8[pos] = p8;
        }
    }
}

// --- Fallback tiers 3/4 ---
constexpr int SCAN_BLOCK = 256;
constexpr int SCAN_ITEMS = 8;
constexpr int SCAN_CHUNK = SCAN_BLOCK * SCAN_ITEMS;

__global__ void __launch_bounds__(256) hist_kernel(
        const int* __restrict__ dst, int* __restrict__ counts, int E) {
    int e = blockIdx.x * blockDim.x + threadIdx.x;
    if (e < E) atomicAdd(&counts[dst[e]], 1);
}
__global__ void __launch_bounds__(SCAN_BLOCK) block_sum_kernel(
        const int* __restrict__ counts, int* __restrict__ bsums, int N) {
    __shared__ int sdata[SCAN_BLOCK];
    int base = blockIdx.x * SCAN_CHUNK;
    int sum = 0;
    for (int j = 0; j < SCAN_ITEMS; ++j) {
        int idx = base + j * SCAN_BLOCK + threadIdx.x;
        if (idx < N) sum += counts[idx];
    }
    sdata[threadIdx.x] = sum;
    __syncthreads();
    for (int off = SCAN_BLOCK / 2; off > 0; off >>= 1) {
        if (threadIdx.x < off) sdata[threadIdx.x] += sdata[threadIdx.x + off];
        __syncthreads();
    }
    if (threadIdx.x == 0) bsums[blockIdx.x] = sdata[0];
}
__global__ void scan_bsums_kernel(int* __restrict__ bsums, int nb) {
    if (threadIdx.x == 0 && blockIdx.x == 0) {
        int acc = 0;
        for (int i = 0; i < nb; ++i) { int v = bsums[i]; bsums[i] = acc; acc += v; }
    }
}
__global__ void __launch_bounds__(SCAN_BLOCK) scan_final_kernel(
        const int* __restrict__ counts, const int* __restrict__ bsums,
        int* __restrict__ offsets, int* __restrict__ cursors, int N, int E) {
    __shared__ int sdata[SCAN_BLOCK];
    int base = blockIdx.x * SCAN_CHUNK + threadIdx.x * SCAN_ITEMS;
    int local[SCAN_ITEMS];
    int tsum = 0;
    for (int j = 0; j < SCAN_ITEMS; ++j) {
        int idx = base + j;
        int v = (idx < N) ? counts[idx] : 0;
        local[j] = tsum;
        tsum += v;
    }
    sdata[threadIdx.x] = tsum;
    __syncthreads();
    for (int off = 1; off < SCAN_BLOCK; off <<= 1) {
        int v = (threadIdx.x >= off) ? sdata[threadIdx.x - off] : 0;
        __syncthreads();
        sdata[threadIdx.x] += v;
        __syncthreads();
    }
    int excl = sdata[threadIdx.x] - tsum + bsums[blockIdx.x];
    for (int j = 0; j < SCAN_ITEMS; ++j) {
        int idx = base + j;
        if (idx < N) { int o = excl + local[j]; offsets[idx] = o; cursors[idx] = o; }
    }
    if (blockIdx.x == 0 && threadIdx.x == 0) offsets[N] = E;
}
__global__ void __launch_bounds__(256) scatter_ids_kernel(
        const int* __restrict__ dst, int* __restrict__ cursors,
        int* __restrict__ eids, int E) {
    int e = blockIdx.x * blockDim.x + threadIdx.x;
    if (e < E) { int pos = atomicAdd(&cursors[dst[e]], 1); eids[pos] = e; }
}
__global__ void __launch_bounds__(US) accum_ids_kernel(
        const float* __restrict__ x, const float* __restrict__ sh,
        const int* __restrict__ src, const int* __restrict__ offsets,
        const int* __restrict__ eids, float* __restrict__ out) {
    int n = blockIdx.x;
    int t = threadIdx.x;
    int u = t >> 2, s = t & 3;
    int beg = offsets[n], end = offsets[n + 1];
    float acc = 0.f;
    for (int i = beg; i < end; ++i) {
        int e = eids[i];
        acc += x[src[e] * U_DIM + u] * sh[e * 4 + s];
    }
    out[(size_t)n * US + t] = acc;
}
__global__ void __launch_bounds__(US) atomic_kernel(
        const float* __restrict__ x, const float* __restrict__ sh,
        const int* __restrict__ src, const int* __restrict__ dst,
        float* __restrict__ out, int E) {
    int e = blockIdx.x;
    int t = threadIdx.x;
    float v = x[src[e] * U_DIM + (t >> 2)] * sh[e * 4 + (t & 3)];
    atomicAdd(&out[(size_t)dst[e] * US + t], v);
}

extern "C" void kernel_launch(void* const* d_in, const int* in_sizes, int n_in,
                              void* d_out, int out_size, void* d_ws, size_t ws_size,
                              hipStream_t stream) {
    const float* x  = (const float*)d_in[0];
    const float* sh = (const float*)d_in[1];
    const int* src  = (const int*)d_in[2];
    const int* dst  = (const int*)d_in[3];
    float* out = (float*)d_out;

    const int E = in_sizes[2];
    const int N = in_sizes[0] / U_DIM;
    const int xn4 = in_sizes[0] / 4;
    const int egrid = (E + 255) / 256;
    const int nb = (N + SCAN_CHUNK - 1) / SCAN_CHUNK;

    const int K1 = (N + C1_NPB - 1) >> C1_LOG;
    const int KF = (N + FINE_NPB - 1) >> FINE_LOG;
    const int EPB1 = (E + C1_NBLK - 1) / C1_NBLK;
    size_t need_main = (size_t)E * 24 + (size_t)in_sizes[0] * 2 +
                       (size_t)(N + 1 + 2 * KF + 2 + K1 + 1 +
                                2 * K1 * C1_NBLK) * 4;

    const int K = (N + NPBK - 1) >> LOG_NPBK;
    const int EPB = (E + NBLK - 1) / NBLK;
    size_t need_r7 = (size_t)E * 12 + (size_t)SPILL_E * 12 + (size_t)(N + 1) * 4 +
                     (size_t)(2 * K + 2) * 4 + (size_t)(2 * K * NBLK) * 4 +
                     (size_t)in_sizes[0] * 2;
    size_t need_ids = (size_t)E * 4 + (size_t)(3 * N + 1 + nb) * 4;

    if (K1 <= C1_MAXK && KF <= KF_MAX && N <= (1 << 21) &&
        (in_sizes[0] % 4 == 0) && ws_size >= need_main) {
        uint2* pay8A   = (uint2*)d_ws;
        uint2* pay8B   = pay8A + E;
        int* packedA   = (int*)(pay8B + E);
        int* packedB   = packedA + E;
        unsigned short* xb = (unsigned short*)(packedB + E);
        int* offsets   = (int*)(xb + in_sizes[0]);
        int* ccount_f  = offsets + N + 1;
        int* fbase     = ccount_f + KF;
        int* cbase     = fbase + KF + 1;
        int* cnt       = cbase + K1 + 1;
        int* base_tab  = cnt + K1 * C1_NBLK;

        hipMemsetAsync(ccount_f, 0, sizeof(int) * (size_t)KF, stream);
        xcvt_kernel<<<(xn4 + 255) / 256, 256, 0, stream>>>(
            (const float4*)x, (ushort4*)xb, xn4);
        c1_hist_kernel<<<C1_NBLK, 1024, 0, stream>>>(dst, ccount_f, cnt,
                                                     E, KF, K1, EPB1);
        c1_scan_kernel<<<1, 1024, 0, stream>>>(ccount_f, fbase, cbase, offsets,
                                               KF, K1, N, E);
        c1_cbase_kernel<<<K1, C1_NBLK, 0, stream>>>(cnt, cbase, base_tab);
        c1_scatter_kernel<<<C1_NBLK, 1024, 0, stream>>>(dst, src, (const float4*)sh,
                                                        base_tab, pay8A, packedA,
                                                        E, K1, EPB1);
        // XCD-swizzled c2 grid: 8 slots x ceil(K1/8) parent-rows x 4 siblings
        int c2_grid = 8 * ((K1 + 7) / 8) * 4;
        c2_sort_kernel<<<c2_grid, 512, 0, stream>>>(cbase, fbase, offsets,
                                                    pay8A, packedA, pay8B,
                                                    packedB, N, K1, KF);
        accum_kernel<<<N, US, 0, stream>>>(xb, pay8B, packedB, offsets, out,
                                           0x1FFFFF);
    } else if (K <= MAXK && (in_sizes[0] % 4 == 0) && ws_size >= need_r7) {
        uint2* pay8      = (uint2*)d_ws;
        uint2* spill_pay = pay8 + E;
        int* packed      = (int*)(spill_pay + SPILL_E);
        int* spill_pk    = packed + E;
        int* offsets     = spill_pk + SPILL_E;
        int* ccount      = offsets + N + 1;
        int* cbase       = ccount + K;
        int* cnt         = cbase + K + 1;
        int* base_tab    = cnt + K * NBLK;
        int* spill_cur   = base_tab + K * NBLK;
        unsigned short* xb = (unsigned short*)(spill_cur + 1);

        hipMemsetAsync(ccount, 0, sizeof(int) * (size_t)K, stream);
        xcvt_kernel<<<(xn4 + 255) / 256, 256, 0, stream>>>(
            (const float4*)x, (ushort4*)xb, xn4);
        coarse_hist_kernel<<<NBLK, 1024, 0, stream>>>(dst, ccount, cnt, E, K, EPB);
        coarse_scan_kernel<<<1, 1024, 0, stream>>>(ccount, cbase, offsets,
                                                   spill_cur, K, N, E);
        chunk_base_kernel<<<K, NBLK, 0, stream>>>(cnt, cbase, base_tab);
        coarse_scatter_kernel<<<NBLK, 1024, 0, stream>>>(dst, src, (const float4*)sh,
                                                         base_tab, pay8, packed,
                                                         E, K, EPB);
        fine_sort_kernel<<<K, 512, 0, stream>>>(cbase, offsets, pay8, packed,
                                                spill_pay, spill_pk, spill_cur, N);
        accum_kernel<<<N, US, 0, stream>>>(xb, pay8, packed, offsets, out,
                                           0xFFFFFF);
    } else if (ws_size >= need_ids) {
        int* eids    = (int*)d_ws;
        int* counts  = eids + E;
        int* offsets = counts + N;
        int* cursors = offsets + N + 1;
        int* bsums   = cursors + N;

        hipMemsetAsync(counts, 0, sizeof(int) * (size_t)N, stream);
        hist_kernel<<<egrid, 256, 0, stream>>>(dst, counts, E);
        block_sum_kernel<<<nb, SCAN_BLOCK, 0, stream>>>(counts, bsums, N);
        scan_bsums_kernel<<<1, 64, 0, stream>>>(bsums, nb);
        scan_final_kernel<<<nb, SCAN_BLOCK, 0, stream>>>(counts, bsums, offsets, cursors, N, E);
        scatter_ids_kernel<<<egrid, 256, 0, stream>>>(dst, cursors, eids, E);
        accum_ids_kernel<<<N, US, 0, stream>>>(x, sh, src, offsets, eids, out);
    } else {
        hipMemsetAsync(out, 0, sizeof(float) * (size_t)out_size, stream);
        atomic_kernel<<<E, US, 0, stream>>>(x, sh, src, dst, out, E);
    }
}

// Round 14
// 236.395 us; speedup vs baseline: 1.1950x; 1.0653x over previous
//
#include <hip/hip_runtime.h>

// out[n, u*4+s] = sum_{e: dst[e]==n} x[src[e], u] * sh[e, s]
// N=100000, U=32, S=4, E=3200000.
//
// Ledger of lessons:
//  R2: bulk LDS float atomics = ~1 lane/cycle serial floor -> register accum.
//  R4/R5/R7: scattered writes into >~400 streams/block = 4.3x HBM write amp.
//  R8: few deep-serial blocks (17% occ) lose to 100k shallow blocks.
//  R9/R13: xb (6.4MB) is L3-resident; accum FETCH is L2-fill, NOT HBM-bound.
//      accum is VALU-issue-bound (56% busy).
//  R10: NT loads on broadcast/shared streams re-fetch lines (FETCH +11MB).
//  R11: contiguous per-lane quarters + 4 independent gathers: 99us accum.
//  R12: 16-way edge split: reduction fixed-cost swamps ~1-iter loops.
//  R13: c2 XCD-swizzle bet on undefined block->XCD mapping: -14us. Reverted.
// R14: accum uses v_pk_fma_f32 (float2 ext-vector fma) + 2 acc banks.

#define U_DIM 32
#define US 128

typedef float v2f __attribute__((ext_vector_type(2)));

__device__ inline unsigned f2bf(float f) {          // RNE float->bf16 bits
    unsigned u = __float_as_uint(f);
    return (u + 0x7FFF + ((u >> 16) & 1)) >> 16;
}
__device__ inline float bfl(unsigned w) { return __uint_as_float(w << 16); }
__device__ inline float bfh(unsigned w) { return __uint_as_float(w & 0xFFFF0000u); }

__global__ void __launch_bounds__(256) xcvt_kernel(
        const float4* __restrict__ x4, ushort4* __restrict__ xb4, int n4) {
    int i = blockIdx.x * 256 + threadIdx.x;
    if (i < n4) {
        float4 v = x4[i];
        ushort4 r;
        r.x = (unsigned short)f2bf(v.x);
        r.y = (unsigned short)f2bf(v.y);
        r.z = (unsigned short)f2bf(v.z);
        r.w = (unsigned short)f2bf(v.w);
        xb4[i] = r;
    }
}

// =================== PRIMARY PATH ===================
#define C1_LOG 9
#define C1_NPB 512
#define C1_MAXK 256
#define C1_NBLK 256
#define FINE_LOG 7
#define FINE_NPB 128
#define KF_MAX 1024
#define SCAP 5120             // LDS-staged edges per fine bucket (mean 4082)

// Fine-granularity (128-node) histogram; also per-chunk coarse counts.
__global__ void __launch_bounds__(1024) c1_hist_kernel(
        const int* __restrict__ dst, int* __restrict__ ccount_f,
        int* __restrict__ cnt, int E, int KF, int K1, int EPB) {
    __shared__ int h[KF_MAX];
    for (int b = threadIdx.x; b < KF; b += 1024) h[b] = 0;
    __syncthreads();
    int base = blockIdx.x * EPB;
    int lim = min(EPB, E - base);
    for (int i = threadIdx.x; i < lim; i += 1024)
        atomicAdd(&h[dst[base + i] >> FINE_LOG], 1);
    __syncthreads();
    for (int b = threadIdx.x; b < KF; b += 1024) {
        int c = h[b];
        if (c) atomicAdd(&ccount_f[b], c);
    }
    for (int b = threadIdx.x; b < K1; b += 1024) {
        int c = 0;
        #pragma unroll
        for (int k = 0; k < 4; ++k) {
            int f = 4 * b + k;
            if (f < KF) c += h[f];
        }
        cnt[b * C1_NBLK + blockIdx.x] = c;
    }
}

// One scan over KF fine counts -> fbase; cbase derived; offsets[N]=E.
__global__ void __launch_bounds__(1024) c1_scan_kernel(
        const int* __restrict__ ccount_f, int* __restrict__ fbase,
        int* __restrict__ cbase, int* __restrict__ offsets,
        int KF, int K1, int N, int E) {
    __shared__ int sc[1024];
    int t = threadIdx.x;
    int v = (t < KF) ? ccount_f[t] : 0;
    sc[t] = v;
    __syncthreads();
    for (int off = 1; off < 1024; off <<= 1) {
        int w = (t >= off) ? sc[t - off] : 0;
        __syncthreads();
        sc[t] += w;
        __syncthreads();
    }
    if (t < KF) fbase[t] = sc[t] - v;
    __syncthreads();
    if (t < K1) {
        int f = 4 * t;
        cbase[t] = (f < KF) ? (sc[f] - ccount_f[f]) : E;
    }
    if (t == 0) { fbase[KF] = E; cbase[K1] = E; offsets[N] = E; }
}

__global__ void __launch_bounds__(C1_NBLK) c1_cbase_kernel(
        const int* __restrict__ cnt, const int* __restrict__ cbase,
        int* __restrict__ base_tab) {
    __shared__ int sc[C1_NBLK];
    int b = blockIdx.x;
    int t = threadIdx.x;
    int v = cnt[b * C1_NBLK + t];
    sc[t] = v;
    __syncthreads();
    for (int off = 1; off < C1_NBLK; off <<= 1) {
        int w = (t >= off) ? sc[t - off] : 0;
        __syncthreads();
        sc[t] += w;
        __syncthreads();
    }
    base_tab[b * C1_NBLK + t] = cbase[b] + sc[t] - v;
}

__global__ void __launch_bounds__(1024) c1_scatter_kernel(
        const int* __restrict__ dst, const int* __restrict__ src,
        const float4* __restrict__ sh, const int* __restrict__ base_tab,
        uint2* __restrict__ pay8A, int* __restrict__ packedA,
        int E, int K1, int EPB) {
    __shared__ int cur[C1_MAXK];
    for (int b = threadIdx.x; b < K1; b += 1024)
        cur[b] = base_tab[b * C1_NBLK + blockIdx.x];
    __syncthreads();
    int base = blockIdx.x * EPB;
    int lim = min(EPB, E - base);
    for (int i = threadIdx.x; i < lim; i += 1024) {
        int e = base + i;
        int d = dst[e];
        int b = d >> C1_LOG;
        int pos = atomicAdd(&cur[b], 1);
        float4 s4 = sh[e];
        pay8A[pos] = make_uint2(f2bf(s4.x) | (f2bf(s4.y) << 16),
                                f2bf(s4.z) | (f2bf(s4.w) << 16));
        packedA[pos] = ((d & (C1_NPB - 1)) << 21) | src[e];
    }
}

// One block per fine bucket: stream parent coarse range (L2/L3-shared with 3
// sibling blocks), filter own sub-bucket, LDS-stage in sorted order, then
// DENSE coalesced write-out to B. Emits offsets[]. (R11-proven form.)
__global__ void __launch_bounds__(512) c2_sort_kernel(
        const int* __restrict__ cbase, const int* __restrict__ fbase,
        int* __restrict__ offsets, const uint2* __restrict__ pay8A,
        const int* __restrict__ packedA, uint2* __restrict__ pay8B,
        int* __restrict__ packedB, int N) {
    __shared__ uint2 spay[SCAP];          // 40 KB
    __shared__ int   spk[SCAP];           // 20 KB
    __shared__ int   hh[FINE_NPB];
    __shared__ int   scur[FINE_NPB];
    int fb = blockIdx.x;
    int t = threadIdx.x;
    int parent = fb >> 2, sub = fb & 3;
    int cbeg = cbase[parent], cend = cbase[parent + 1];
    int fbeg = fbase[fb];
    int cnt = fbase[fb + 1] - fbeg;
    if (t < FINE_NPB) hh[t] = 0;
    __syncthreads();
    for (int i = cbeg + t; i < cend; i += 512) {
        int nc = (packedA[i] >> 21) & (C1_NPB - 1);
        if ((nc >> FINE_LOG) == sub)
            atomicAdd(&hh[nc & (FINE_NPB - 1)], 1);
    }
    __syncthreads();
    int v = (t < FINE_NPB) ? hh[t] : 0;
    if (t < FINE_NPB) hh[t] = v;
    __syncthreads();
    for (int off = 1; off < FINE_NPB; off <<= 1) {
        int w = (t < FINE_NPB && t >= off) ? hh[t - off] : 0;
        __syncthreads();
        if (t < FINE_NPB) hh[t] += w;
        __syncthreads();
    }
    if (t < FINE_NPB) {
        int excl = hh[t] - v;
        scur[t] = excl;
        int node = (fb << FINE_LOG) + t;
        if (node < N) offsets[node] = fbeg + excl;
    }
    __syncthreads();
    for (int i = cbeg + t; i < cend; i += 512) {
        int pk = packedA[i];
        int nc = (pk >> 21) & (C1_NPB - 1);
        if ((nc >> FINE_LOG) == sub) {
            int pos = atomicAdd(&scur[nc & (FINE_NPB - 1)], 1);
            uint2 p8 = pay8A[i];
            if (pos < SCAP) { spk[pos] = pk; spay[pos] = p8; }
            else { packedB[fbeg + pos] = pk; pay8B[fbeg + pos] = p8; }
        }
    }
    __syncthreads();
    int lim = min(cnt, SCAP);
    for (int i = t; i < lim; i += 512) {
        packedB[fbeg + i] = spk[i];
        pay8B[fbeg + i] = spay[i];
    }
}

// One block per node, 128 threads: u = t&31, g = t>>5 owns a CONTIGUOUS
// quarter of the node's edges. Unroll-4, 4 independent xb gathers in flight,
// v_pk_fma_f32 via float2 ext-vectors, 2 accumulator banks (R14).
__global__ void __launch_bounds__(US) accum_kernel(
        const unsigned short* __restrict__ xb, const uint2* __restrict__ pay8,
        const int* __restrict__ packed, const int* __restrict__ offsets,
        float* __restrict__ out, int smask) {
    int n = blockIdx.x;
    int t = threadIdx.x;
    int u = t & 31;
    int g = t >> 5;
    int beg = offsets[n], end = offsets[n + 1];
    int len = end - beg;
    int q0 = beg + ((len * g) >> 2);
    int q1 = beg + ((len * (g + 1)) >> 2);
    v2f a01 = {0.f, 0.f}, a23 = {0.f, 0.f};
    v2f c01 = {0.f, 0.f}, c23 = {0.f, 0.f};
    int i = q0;
    for (; i + 3 < q1; i += 4) {
        int pk0 = packed[i], pk1 = packed[i + 1];
        int pk2 = packed[i + 2], pk3 = packed[i + 3];
        uint2 qv0 = pay8[i], qv1 = pay8[i + 1];
        uint2 qv2 = pay8[i + 2], qv3 = pay8[i + 3];
        float x0 = bfl((unsigned)xb[(size_t)(pk0 & smask) * U_DIM + u]);
        float x1 = bfl((unsigned)xb[(size_t)(pk1 & smask) * U_DIM + u]);
        float x2 = bfl((unsigned)xb[(size_t)(pk2 & smask) * U_DIM + u]);
        float x3 = bfl((unsigned)xb[(size_t)(pk3 & smask) * U_DIM + u]);
        v2f x0v = {x0, x0}, x1v = {x1, x1}, x2v = {x2, x2}, x3v = {x3, x3};
        a01 = __builtin_elementwise_fma(x0v, (v2f){bfl(qv0.x), bfh(qv0.x)}, a01);
        a23 = __builtin_elementwise_fma(x0v, (v2f){bfl(qv0.y), bfh(qv0.y)}, a23);
        c01 = __builtin_elementwise_fma(x1v, (v2f){bfl(qv1.x), bfh(qv1.x)}, c01);
        c23 = __builtin_elementwise_fma(x1v, (v2f){bfl(qv1.y), bfh(qv1.y)}, c23);
        a01 = __builtin_elementwise_fma(x2v, (v2f){bfl(qv2.x), bfh(qv2.x)}, a01);
        a23 = __builtin_elementwise_fma(x2v, (v2f){bfl(qv2.y), bfh(qv2.y)}, a23);
        c01 = __builtin_elementwise_fma(x3v, (v2f){bfl(qv3.x), bfh(qv3.x)}, c01);
        c23 = __builtin_elementwise_fma(x3v, (v2f){bfl(qv3.y), bfh(qv3.y)}, c23);
    }
    for (; i < q1; ++i) {
        int pk = packed[i];
        uint2 qv = pay8[i];
        float xv = bfl((unsigned)xb[(size_t)(pk & smask) * U_DIM + u]);
        v2f xvv = {xv, xv};
        a01 = __builtin_elementwise_fma(xvv, (v2f){bfl(qv.x), bfh(qv.x)}, a01);
        a23 = __builtin_elementwise_fma(xvv, (v2f){bfl(qv.y), bfh(qv.y)}, a23);
    }
    float a0 = a01.x + c01.x, a1 = a01.y + c01.y;
    float a2 = a23.x + c23.x, a3 = a23.y + c23.y;
    a0 += __shfl_xor(a0, 32);
    a1 += __shfl_xor(a1, 32);
    a2 += __shfl_xor(a2, 32);
    a3 += __shfl_xor(a3, 32);
    __shared__ float red[US];
    int w = t >> 6, l = t & 63;
    if (w == 1 && l < 32) {
        red[l * 4 + 0] = a0; red[l * 4 + 1] = a1;
        red[l * 4 + 2] = a2; red[l * 4 + 3] = a3;
    }
    __syncthreads();
    if (w == 0 && l < 32) {
        float4 o = make_float4(a0 + red[l * 4 + 0], a1 + red[l * 4 + 1],
                               a2 + red[l * 4 + 2], a3 + red[l * 4 + 3]);
        *reinterpret_cast<float4*>(&out[(size_t)n * US + l * 4]) = o;
    }
}

// =================== TIER-2: proven R7 path ===================
#define LOG_NPBK 7
#define NPBK 128
#define MAXK 1024
#define NBLK 256
#define CAP 5120
#define SPILL_E 1000000

__global__ void __launch_bounds__(1024) coarse_hist_kernel(
        const int* __restrict__ dst, int* __restrict__ ccount,
        int* __restrict__ cnt, int E, int K, int EPB) {
    __shared__ int h[MAXK];
    for (int b = threadIdx.x; b < K; b += 1024) h[b] = 0;
    __syncthreads();
    int base = blockIdx.x * EPB;
    int lim = min(EPB, E - base);
    for (int i = threadIdx.x; i < lim; i += 1024)
        atomicAdd(&h[dst[base + i] >> LOG_NPBK], 1);
    __syncthreads();
    for (int b = threadIdx.x; b < K; b += 1024) {
        int c = h[b];
        cnt[b * NBLK + blockIdx.x] = c;
        if (c) atomicAdd(&ccount[b], c);
    }
}

__global__ void __launch_bounds__(1024) coarse_scan_kernel(
        const int* __restrict__ ccount, int* __restrict__ cbase,
        int* __restrict__ offsets, int* __restrict__ spill_cursor,
        int K, int N, int E) {
    __shared__ int sc[1024];
    int t = threadIdx.x;
    int v = (t < K) ? ccount[t] : 0;
    sc[t] = v;
    __syncthreads();
    for (int off = 1; off < 1024; off <<= 1) {
        int w = (t >= off) ? sc[t - off] : 0;
        __syncthreads();
        sc[t] += w;
        __syncthreads();
    }
    if (t < K) cbase[t] = sc[t] - v;
    if (t == 0) { cbase[K] = E; offsets[N] = E; *spill_cursor = 0; }
}

__global__ void __launch_bounds__(NBLK) chunk_base_kernel(
        const int* __restrict__ cnt, const int* __restrict__ cbase,
        int* __restrict__ base_tab) {
    __shared__ int sc[NBLK];
    int b = blockIdx.x;
    int t = threadIdx.x;
    int v = cnt[b * NBLK + t];
    sc[t] = v;
    __syncthreads();
    for (int off = 1; off < NBLK; off <<= 1) {
        int w = (t >= off) ? sc[t - off] : 0;
        __syncthreads();
        sc[t] += w;
        __syncthreads();
    }
    base_tab[b * NBLK + t] = cbase[b] + sc[t] - v;
}

__global__ void __launch_bounds__(1024) coarse_scatter_kernel(
        const int* __restrict__ dst, const int* __restrict__ src,
        const float4* __restrict__ sh, const int* __restrict__ base_tab,
        uint2* __restrict__ pay8, int* __restrict__ packed,
        int E, int K, int EPB) {
    __shared__ int cur[MAXK];
    for (int b = threadIdx.x; b < K; b += 1024)
        cur[b] = base_tab[b * NBLK + blockIdx.x];
    __syncthreads();
    int base = blockIdx.x * EPB;
    int lim = min(EPB, E - base);
    for (int i = threadIdx.x; i < lim; i += 1024) {
        int e = base + i;
        int d = dst[e];
        int b = d >> LOG_NPBK;
        int pos = atomicAdd(&cur[b], 1);
        float4 s4 = sh[e];
        pay8[pos] = make_uint2(f2bf(s4.x) | (f2bf(s4.y) << 16),
                               f2bf(s4.z) | (f2bf(s4.w) << 16));
        packed[pos] = ((d & (NPBK - 1)) << 24) | src[e];
    }
}

__global__ void __launch_bounds__(512) fine_sort_kernel(
        const int* __restrict__ cbase, int* __restrict__ offsets,
        uint2* __restrict__ pay8, int* __restrict__ packed,
        uint2* __restrict__ spill_pay, int* __restrict__ spill_pk,
        int* __restrict__ spill_cursor, int N) {
    __shared__ uint2 spay[CAP];
    __shared__ int   spk[CAP];
    __shared__ int   cnt_[NPBK];
    __shared__ int   sc[NPBK];
    __shared__ int   sbase_s;
    int b = blockIdx.x;
    int t = threadIdx.x;
    int cbeg = cbase[b], cend = cbase[b + 1];
    int cnt = cend - cbeg;
    if (t == 0) sbase_s = (cnt > CAP) ? atomicAdd(spill_cursor, cnt - CAP) : 0;
    if (t < NPBK) cnt_[t] = 0;
    __syncthreads();
    for (int i = t; i < cnt; i += 512) {
        int pk = packed[cbeg + i];
        uint2 p8 = pay8[cbeg + i];
        atomicAdd(&cnt_[(pk >> 24) & (NPBK - 1)], 1);
        if (i < CAP) { spk[i] = pk; spay[i] = p8; }
        else {
            int sp = sbase_s + (i - CAP);
            if (sp < SPILL_E) { spill_pk[sp] = pk; spill_pay[sp] = p8; }
        }
    }
    __syncthreads();
    int v = (t < NPBK) ? cnt_[t] : 0;
    if (t < NPBK) sc[t] = v;
    __syncthreads();
    for (int off = 1; off < NPBK; off <<= 1) {
        int w = (t < NPBK && t >= off) ? sc[t - off] : 0;
        __syncthreads();
        if (t < NPBK) sc[t] += w;
        __syncthreads();
    }
    if (t < NPBK) {
        int ex = sc[t] - v;
        int node = (b << LOG_NPBK) + t;
        if (node <= N) offsets[node] = cbeg + ex;
        cnt_[t] = ex;
    }
    __syncthreads();
    for (int i = t; i < cnt; i += 512) {
        int pk; uint2 p8;
        bool ok = true;
        if (i < CAP) { pk = spk[i]; p8 = spay[i]; }
        else {
            int sp = sbase_s + (i - CAP);
            ok = (sp < SPILL_E);
            if (ok) { pk = spill_pk[sp]; p8 = spill_pay[sp]; }
        }
        if (ok) {
            int pos = cbeg + atomicAdd(&cnt_[(pk >> 24) & (NPBK - 1)], 1);
            packed[pos] = pk;
            pay8[pos] = p8;
        }
    }
}

// --- Fallback tiers 3/4 ---
constexpr int SCAN_BLOCK = 256;
constexpr int SCAN_ITEMS = 8;
constexpr int SCAN_CHUNK = SCAN_BLOCK * SCAN_ITEMS;

__global__ void __launch_bounds__(256) hist_kernel(
        const int* __restrict__ dst, int* __restrict__ counts, int E) {
    int e = blockIdx.x * blockDim.x + threadIdx.x;
    if (e < E) atomicAdd(&counts[dst[e]], 1);
}
__global__ void __launch_bounds__(SCAN_BLOCK) block_sum_kernel(
        const int* __restrict__ counts, int* __restrict__ bsums, int N) {
    __shared__ int sdata[SCAN_BLOCK];
    int base = blockIdx.x * SCAN_CHUNK;
    int sum = 0;
    for (int j = 0; j < SCAN_ITEMS; ++j) {
        int idx = base + j * SCAN_BLOCK + threadIdx.x;
        if (idx < N) sum += counts[idx];
    }
    sdata[threadIdx.x] = sum;
    __syncthreads();
    for (int off = SCAN_BLOCK / 2; off > 0; off >>= 1) {
        if (threadIdx.x < off) sdata[threadIdx.x] += sdata[threadIdx.x + off];
        __syncthreads();
    }
    if (threadIdx.x == 0) bsums[blockIdx.x] = sdata[0];
}
__global__ void scan_bsums_kernel(int* __restrict__ bsums, int nb) {
    if (threadIdx.x == 0 && blockIdx.x == 0) {
        int acc = 0;
        for (int i = 0; i < nb; ++i) { int v = bsums[i]; bsums[i] = acc; acc += v; }
    }
}
__global__ void __launch_bounds__(SCAN_BLOCK) scan_final_kernel(
        const int* __restrict__ counts, const int* __restrict__ bsums,
        int* __restrict__ offsets, int* __restrict__ cursors, int N, int E) {
    __shared__ int sdata[SCAN_BLOCK];
    int base = blockIdx.x * SCAN_CHUNK + threadIdx.x * SCAN_ITEMS;
    int local[SCAN_ITEMS];
    int tsum = 0;
    for (int j = 0; j < SCAN_ITEMS; ++j) {
        int idx = base + j;
        int v = (idx < N) ? counts[idx] : 0;
        local[j] = tsum;
        tsum += v;
    }
    sdata[threadIdx.x] = tsum;
    __syncthreads();
    for (int off = 1; off < SCAN_BLOCK; off <<= 1) {
        int v = (threadIdx.x >= off) ? sdata[threadIdx.x - off] : 0;
        __syncthreads();
        sdata[threadIdx.x] += v;
        __syncthreads();
    }
    int excl = sdata[threadIdx.x] - tsum + bsums[blockIdx.x];
    for (int j = 0; j < SCAN_ITEMS; ++j) {
        int idx = base + j;
        if (idx < N) { int o = excl + local[j]; offsets[idx] = o; cursors[idx] = o; }
    }
    if (blockIdx.x == 0 && threadIdx.x == 0) offsets[N] = E;
}
__global__ void __launch_bounds__(256) scatter_ids_kernel(
        const int* __restrict__ dst, int* __restrict__ cursors,
        int* __restrict__ eids, int E) {
    int e = blockIdx.x * blockDim.x + threadIdx.x;
    if (e < E) { int pos = atomicAdd(&cursors[dst[e]], 1); eids[pos] = e; }
}
__global__ void __launch_bounds__(US) accum_ids_kernel(
        const float* __restrict__ x, const float* __restrict__ sh,
        const int* __restrict__ src, const int* __restrict__ offsets,
        const int* __restrict__ eids, float* __restrict__ out) {
    int n = blockIdx.x;
    int t = threadIdx.x;
    int u = t >> 2, s = t & 3;
    int beg = offsets[n], end = offsets[n + 1];
    float acc = 0.f;
    for (int i = beg; i < end; ++i) {
        int e = eids[i];
        acc += x[src[e] * U_DIM + u] * sh[e * 4 + s];
    }
    out[(size_t)n * US + t] = acc;
}
__global__ void __launch_bounds__(US) atomic_kernel(
        const float* __restrict__ x, const float* __restrict__ sh,
        const int* __restrict__ src, const int* __restrict__ dst,
        float* __restrict__ out, int E) {
    int e = blockIdx.x;
    int t = threadIdx.x;
    float v = x[src[e] * U_DIM + (t >> 2)] * sh[e * 4 + (t & 3)];
    atomicAdd(&out[(size_t)dst[e] * US + t], v);
}

extern "C" void kernel_launch(void* const* d_in, const int* in_sizes, int n_in,
                              void* d_out, int out_size, void* d_ws, size_t ws_size,
                              hipStream_t stream) {
    const float* x  = (const float*)d_in[0];
    const float* sh = (const float*)d_in[1];
    const int* src  = (const int*)d_in[2];
    const int* dst  = (const int*)d_in[3];
    float* out = (float*)d_out;

    const int E = in_sizes[2];
    const int N = in_sizes[0] / U_DIM;
    const int xn4 = in_sizes[0] / 4;
    const int egrid = (E + 255) / 256;
    const int nb = (N + SCAN_CHUNK - 1) / SCAN_CHUNK;

    const int K1 = (N + C1_NPB - 1) >> C1_LOG;
    const int KF = (N + FINE_NPB - 1) >> FINE_LOG;
    const int EPB1 = (E + C1_NBLK - 1) / C1_NBLK;
    size_t need_main = (size_t)E * 24 + (size_t)in_sizes[0] * 2 +
                       (size_t)(N + 1 + 2 * KF + 2 + K1 + 1 +
                                2 * K1 * C1_NBLK) * 4;

    const int K = (N + NPBK - 1) >> LOG_NPBK;
    const int EPB = (E + NBLK - 1) / NBLK;
    size_t need_r7 = (size_t)E * 12 + (size_t)SPILL_E * 12 + (size_t)(N + 1) * 4 +
                     (size_t)(2 * K + 2) * 4 + (size_t)(2 * K * NBLK) * 4 +
                     (size_t)in_sizes[0] * 2;
    size_t need_ids = (size_t)E * 4 + (size_t)(3 * N + 1 + nb) * 4;

    if (K1 <= C1_MAXK && KF <= KF_MAX && N <= (1 << 21) &&
        (in_sizes[0] % 4 == 0) && ws_size >= need_main) {
        uint2* pay8A   = (uint2*)d_ws;
        uint2* pay8B   = pay8A + E;
        int* packedA   = (int*)(pay8B + E);
        int* packedB   = packedA + E;
        unsigned short* xb = (unsigned short*)(packedB + E);
        int* offsets   = (int*)(xb + in_sizes[0]);
        int* ccount_f  = offsets + N + 1;
        int* fbase     = ccount_f + KF;
        int* cbase     = fbase + KF + 1;
        int* cnt       = cbase + K1 + 1;
        int* base_tab  = cnt + K1 * C1_NBLK;

        hipMemsetAsync(ccount_f, 0, sizeof(int) * (size_t)KF, stream);
        xcvt_kernel<<<(xn4 + 255) / 256, 256, 0, stream>>>(
            (const float4*)x, (ushort4*)xb, xn4);
        c1_hist_kernel<<<C1_NBLK, 1024, 0, stream>>>(dst, ccount_f, cnt,
                                                     E, KF, K1, EPB1);
        c1_scan_kernel<<<1, 1024, 0, stream>>>(ccount_f, fbase, cbase, offsets,
                                               KF, K1, N, E);
        c1_cbase_kernel<<<K1, C1_NBLK, 0, stream>>>(cnt, cbase, base_tab);
        c1_scatter_kernel<<<C1_NBLK, 1024, 0, stream>>>(dst, src, (const float4*)sh,
                                                        base_tab, pay8A, packedA,
                                                        E, K1, EPB1);
        c2_sort_kernel<<<KF, 512, 0, stream>>>(cbase, fbase, offsets,
                                               pay8A, packedA, pay8B, packedB, N);
        accum_kernel<<<N, US, 0, stream>>>(xb, pay8B, packedB, offsets, out,
                                           0x1FFFFF);
    } else if (K <= MAXK && (in_sizes[0] % 4 == 0) && ws_size >= need_r7) {
        uint2* pay8      = (uint2*)d_ws;
        uint2* spill_pay = pay8 + E;
        int* packed      = (int*)(spill_pay + SPILL_E);
        int* spill_pk    = packed + E;
        int* offsets     = spill_pk + SPILL_E;
        int* ccount      = offsets + N + 1;
        int* cbase       = ccount + K;
        int* cnt         = cbase + K + 1;
        int* base_tab    = cnt + K * NBLK;
        int* spill_cur   = base_tab + K * NBLK;
        unsigned short* xb = (unsigned short*)(spill_cur + 1);

        hipMemsetAsync(ccount, 0, sizeof(int) * (size_t)K, stream);
        xcvt_kernel<<<(xn4 + 255) / 256, 256, 0, stream>>>(
            (const float4*)x, (ushort4*)xb, xn4);
        coarse_hist_kernel<<<NBLK, 1024, 0, stream>>>(dst, ccount, cnt, E, K, EPB);
        coarse_scan_kernel<<<1, 1024, 0, stream>>>(ccount, cbase, offsets,
                                                   spill_cur, K, N, E);
        chunk_base_kernel<<<K, NBLK, 0, stream>>>(cnt, cbase, base_tab);
        coarse_scatter_kernel<<<NBLK, 1024, 0, stream>>>(dst, src, (const float4*)sh,
                                                         base_tab, pay8, packed,
                                                         E, K, EPB);
        fine_sort_kernel<<<K, 512, 0, stream>>>(cbase, offsets, pay8, packed,
                                                spill_pay, spill_pk, spill_cur, N);
        accum_kernel<<<N, US, 0, stream>>>(xb, pay8, packed, offsets, out,
                                           0xFFFFFF);
    } else if (ws_size >= need_ids) {
        int* eids    = (int*)d_ws;
        int* counts  = eids + E;
        int* offsets = counts + N;
        int* cursors = offsets + N + 1;
        int* bsums   = cursors + N;

        hipMemsetAsync(counts, 0, sizeof(int) * (size_t)N, stream);
        hist_kernel<<<egrid, 256, 0, stream>>>(dst, counts, E);
        block_sum_kernel<<<nb, SCAN_BLOCK, 0, stream>>>(counts, bsums, N);
        scan_bsums_kernel<<<1, 64, 0, stream>>>(bsums, nb);
        scan_final_kernel<<<nb, SCAN_BLOCK, 0, stream>>>(counts, bsums, offsets, cursors, N, E);
        scatter_ids_kernel<<<egrid, 256, 0, stream>>>(dst, cursors, eids, E);
        accum_ids_kernel<<<N, US, 0, stream>>>(x, sh, src, offsets, eids, out);
    } else {
        hipMemsetAsync(out, 0, sizeof(float) * (size_t)out_size, stream);
        atomic_kernel<<<E, US, 0, stream>>>(x, sh, src, dst, out, E);
    }
}

// Round 15
// 225.451 us; speedup vs baseline: 1.2530x; 1.0485x over previous
//
#include <hip/hip_runtime.h>

// out[n, u*4+s] = sum_{e: dst[e]==n} x[src[e], u] * sh[e, s]
// N=100000, U=32, S=4, E=3200000.
//
// Ledger of lessons:
//  R2: bulk LDS float atomics = ~1 lane/cycle serial floor -> register accum.
//  R4/R5/R7: scattered writes into >~400 streams/block = 4.3x HBM write amp.
//  R8: few deep-serial blocks (17% occ) lose to 100k shallow blocks.
//  R9/R13: xb (6.4MB) is L3-resident; accum FETCH is L2-fill, NOT HBM-bound.
//  R10: NT loads on broadcast/shared streams re-fetch lines (FETCH +11MB).
//  R11: contiguous per-lane quarters + 4 independent gathers: 99us accum.
//  R12: 16-way edge split: reduction fixed-cost swamps ~1-iter loops.
//  R13: c2 XCD-swizzle bet on undefined block->XCD mapping: -14us. Reverted.
//  R14: pk-fma neutral -> accum not FMA-throughput-bound; it's per-block
//       fixed overhead (barrier + LDS exchange + idle store wave).
// R15: accum = ONE WAVE PER NODE (4 nodes / 256-thr block): no LDS, no
//      syncthreads; g=lane>>5 owns a contiguous HALF (16 edges, 4 iters);
//      single shfl_xor(32) reduce; lanes 0-31 store 512B contiguous.

#define U_DIM 32
#define US 128

__device__ inline unsigned f2bf(float f) {          // RNE float->bf16 bits
    unsigned u = __float_as_uint(f);
    return (u + 0x7FFF + ((u >> 16) & 1)) >> 16;
}
__device__ inline float bfl(unsigned w) { return __uint_as_float(w << 16); }
__device__ inline float bfh(unsigned w) { return __uint_as_float(w & 0xFFFF0000u); }

__global__ void __launch_bounds__(256) xcvt_kernel(
        const float4* __restrict__ x4, ushort4* __restrict__ xb4, int n4) {
    int i = blockIdx.x * 256 + threadIdx.x;
    if (i < n4) {
        float4 v = x4[i];
        ushort4 r;
        r.x = (unsigned short)f2bf(v.x);
        r.y = (unsigned short)f2bf(v.y);
        r.z = (unsigned short)f2bf(v.z);
        r.w = (unsigned short)f2bf(v.w);
        xb4[i] = r;
    }
}

// =================== PRIMARY PATH ===================
#define C1_LOG 9
#define C1_NPB 512
#define C1_MAXK 256
#define C1_NBLK 256
#define FINE_LOG 7
#define FINE_NPB 128
#define KF_MAX 1024
#define SCAP 5120             // LDS-staged edges per fine bucket (mean 4082)

// Fine-granularity (128-node) histogram; also per-chunk coarse counts.
__global__ void __launch_bounds__(1024) c1_hist_kernel(
        const int* __restrict__ dst, int* __restrict__ ccount_f,
        int* __restrict__ cnt, int E, int KF, int K1, int EPB) {
    __shared__ int h[KF_MAX];
    for (int b = threadIdx.x; b < KF; b += 1024) h[b] = 0;
    __syncthreads();
    int base = blockIdx.x * EPB;
    int lim = min(EPB, E - base);
    for (int i = threadIdx.x; i < lim; i += 1024)
        atomicAdd(&h[dst[base + i] >> FINE_LOG], 1);
    __syncthreads();
    for (int b = threadIdx.x; b < KF; b += 1024) {
        int c = h[b];
        if (c) atomicAdd(&ccount_f[b], c);
    }
    for (int b = threadIdx.x; b < K1; b += 1024) {
        int c = 0;
        #pragma unroll
        for (int k = 0; k < 4; ++k) {
            int f = 4 * b + k;
            if (f < KF) c += h[f];
        }
        cnt[b * C1_NBLK + blockIdx.x] = c;
    }
}

// One scan over KF fine counts -> fbase; cbase derived; offsets[N]=E.
__global__ void __launch_bounds__(1024) c1_scan_kernel(
        const int* __restrict__ ccount_f, int* __restrict__ fbase,
        int* __restrict__ cbase, int* __restrict__ offsets,
        int KF, int K1, int N, int E) {
    __shared__ int sc[1024];
    int t = threadIdx.x;
    int v = (t < KF) ? ccount_f[t] : 0;
    sc[t] = v;
    __syncthreads();
    for (int off = 1; off < 1024; off <<= 1) {
        int w = (t >= off) ? sc[t - off] : 0;
        __syncthreads();
        sc[t] += w;
        __syncthreads();
    }
    if (t < KF) fbase[t] = sc[t] - v;
    __syncthreads();
    if (t < K1) {
        int f = 4 * t;
        cbase[t] = (f < KF) ? (sc[f] - ccount_f[f]) : E;
    }
    if (t == 0) { fbase[KF] = E; cbase[K1] = E; offsets[N] = E; }
}

__global__ void __launch_bounds__(C1_NBLK) c1_cbase_kernel(
        const int* __restrict__ cnt, const int* __restrict__ cbase,
        int* __restrict__ base_tab) {
    __shared__ int sc[C1_NBLK];
    int b = blockIdx.x;
    int t = threadIdx.x;
    int v = cnt[b * C1_NBLK + t];
    sc[t] = v;
    __syncthreads();
    for (int off = 1; off < C1_NBLK; off <<= 1) {
        int w = (t >= off) ? sc[t - off] : 0;
        __syncthreads();
        sc[t] += w;
        __syncthreads();
    }
    base_tab[b * C1_NBLK + t] = cbase[b] + sc[t] - v;
}

__global__ void __launch_bounds__(1024) c1_scatter_kernel(
        const int* __restrict__ dst, const int* __restrict__ src,
        const float4* __restrict__ sh, const int* __restrict__ base_tab,
        uint2* __restrict__ pay8A, int* __restrict__ packedA,
        int E, int K1, int EPB) {
    __shared__ int cur[C1_MAXK];
    for (int b = threadIdx.x; b < K1; b += 1024)
        cur[b] = base_tab[b * C1_NBLK + blockIdx.x];
    __syncthreads();
    int base = blockIdx.x * EPB;
    int lim = min(EPB, E - base);
    for (int i = threadIdx.x; i < lim; i += 1024) {
        int e = base + i;
        int d = dst[e];
        int b = d >> C1_LOG;
        int pos = atomicAdd(&cur[b], 1);
        float4 s4 = sh[e];
        pay8A[pos] = make_uint2(f2bf(s4.x) | (f2bf(s4.y) << 16),
                                f2bf(s4.z) | (f2bf(s4.w) << 16));
        packedA[pos] = ((d & (C1_NPB - 1)) << 21) | src[e];
    }
}

// One block per fine bucket: stream parent coarse range (L2/L3-shared with 3
// sibling blocks), filter own sub-bucket, LDS-stage in sorted order, then
// DENSE coalesced write-out to B. Emits offsets[]. (R11-proven form.)
__global__ void __launch_bounds__(512) c2_sort_kernel(
        const int* __restrict__ cbase, const int* __restrict__ fbase,
        int* __restrict__ offsets, const uint2* __restrict__ pay8A,
        const int* __restrict__ packedA, uint2* __restrict__ pay8B,
        int* __restrict__ packedB, int N) {
    __shared__ uint2 spay[SCAP];          // 40 KB
    __shared__ int   spk[SCAP];           // 20 KB
    __shared__ int   hh[FINE_NPB];
    __shared__ int   scur[FINE_NPB];
    int fb = blockIdx.x;
    int t = threadIdx.x;
    int parent = fb >> 2, sub = fb & 3;
    int cbeg = cbase[parent], cend = cbase[parent + 1];
    int fbeg = fbase[fb];
    int cnt = fbase[fb + 1] - fbeg;
    if (t < FINE_NPB) hh[t] = 0;
    __syncthreads();
    for (int i = cbeg + t; i < cend; i += 512) {
        int nc = (packedA[i] >> 21) & (C1_NPB - 1);
        if ((nc >> FINE_LOG) == sub)
            atomicAdd(&hh[nc & (FINE_NPB - 1)], 1);
    }
    __syncthreads();
    int v = (t < FINE_NPB) ? hh[t] : 0;
    if (t < FINE_NPB) hh[t] = v;
    __syncthreads();
    for (int off = 1; off < FINE_NPB; off <<= 1) {
        int w = (t < FINE_NPB && t >= off) ? hh[t - off] : 0;
        __syncthreads();
        if (t < FINE_NPB) hh[t] += w;
        __syncthreads();
    }
    if (t < FINE_NPB) {
        int excl = hh[t] - v;
        scur[t] = excl;
        int node = (fb << FINE_LOG) + t;
        if (node < N) offsets[node] = fbeg + excl;
    }
    __syncthreads();
    for (int i = cbeg + t; i < cend; i += 512) {
        int pk = packedA[i];
        int nc = (pk >> 21) & (C1_NPB - 1);
        if ((nc >> FINE_LOG) == sub) {
            int pos = atomicAdd(&scur[nc & (FINE_NPB - 1)], 1);
            uint2 p8 = pay8A[i];
            if (pos < SCAP) { spk[pos] = pk; spay[pos] = p8; }
            else { packedB[fbeg + pos] = pk; pay8B[fbeg + pos] = p8; }
        }
    }
    __syncthreads();
    int lim = min(cnt, SCAP);
    for (int i = t; i < lim; i += 512) {
        packedB[fbeg + i] = spk[i];
        pay8B[fbeg + i] = spay[i];
    }
}

// ONE WAVE PER NODE; 256-thread block covers 4 nodes. No LDS, no barriers.
// Within a wave: u = lane&31, g = lane>>5 owns a contiguous HALF of the
// node's edges. Unroll-4, 4 independent xb gathers in flight (R11 body).
__global__ void __launch_bounds__(256) accum_kernel(
        const unsigned short* __restrict__ xb, const uint2* __restrict__ pay8,
        const int* __restrict__ packed, const int* __restrict__ offsets,
        float* __restrict__ out, int smask, int N) {
    int n = blockIdx.x * 4 + (threadIdx.x >> 6);
    if (n >= N) return;
    int lane = threadIdx.x & 63;
    int u = lane & 31;
    int g = lane >> 5;
    int beg = offsets[n], end = offsets[n + 1];
    int len = end - beg;
    int q0 = beg + ((len * g) >> 1);
    int q1 = beg + ((len * (g + 1)) >> 1);
    float a0 = 0.f, a1 = 0.f, a2 = 0.f, a3 = 0.f;
    int i = q0;
    for (; i + 3 < q1; i += 4) {
        int pk0 = packed[i], pk1 = packed[i + 1];
        int pk2 = packed[i + 2], pk3 = packed[i + 3];
        uint2 qv0 = pay8[i], qv1 = pay8[i + 1];
        uint2 qv2 = pay8[i + 2], qv3 = pay8[i + 3];
        float x0 = bfl((unsigned)xb[(size_t)(pk0 & smask) * U_DIM + u]);
        float x1 = bfl((unsigned)xb[(size_t)(pk1 & smask) * U_DIM + u]);
        float x2 = bfl((unsigned)xb[(size_t)(pk2 & smask) * U_DIM + u]);
        float x3 = bfl((unsigned)xb[(size_t)(pk3 & smask) * U_DIM + u]);
        a0 += x0 * bfl(qv0.x); a1 += x0 * bfh(qv0.x);
        a2 += x0 * bfl(qv0.y); a3 += x0 * bfh(qv0.y);
        a0 += x1 * bfl(qv1.x); a1 += x1 * bfh(qv1.x);
        a2 += x1 * bfl(qv1.y); a3 += x1 * bfh(qv1.y);
        a0 += x2 * bfl(qv2.x); a1 += x2 * bfh(qv2.x);
        a2 += x2 * bfl(qv2.y); a3 += x2 * bfh(qv2.y);
        a0 += x3 * bfl(qv3.x); a1 += x3 * bfh(qv3.x);
        a2 += x3 * bfl(qv3.y); a3 += x3 * bfh(qv3.y);
    }
    for (; i < q1; ++i) {
        int pk = packed[i];
        uint2 qv = pay8[i];
        float xv = bfl((unsigned)xb[(size_t)(pk & smask) * U_DIM + u]);
        a0 += xv * bfl(qv.x); a1 += xv * bfh(qv.x);
        a2 += xv * bfl(qv.y); a3 += xv * bfh(qv.y);
    }
    // fold the two half-ranges (lane ^ 32)
    a0 += __shfl_xor(a0, 32);
    a1 += __shfl_xor(a1, 32);
    a2 += __shfl_xor(a2, 32);
    a3 += __shfl_xor(a3, 32);
    if (g == 0) {
        float4 o = make_float4(a0, a1, a2, a3);
        *reinterpret_cast<float4*>(&out[(size_t)n * US + u * 4]) = o;
    }
}

// =================== TIER-2: proven R7 path ===================
#define LOG_NPBK 7
#define NPBK 128
#define MAXK 1024
#define NBLK 256
#define CAP 5120
#define SPILL_E 1000000

__global__ void __launch_bounds__(1024) coarse_hist_kernel(
        const int* __restrict__ dst, int* __restrict__ ccount,
        int* __restrict__ cnt, int E, int K, int EPB) {
    __shared__ int h[MAXK];
    for (int b = threadIdx.x; b < K; b += 1024) h[b] = 0;
    __syncthreads();
    int base = blockIdx.x * EPB;
    int lim = min(EPB, E - base);
    for (int i = threadIdx.x; i < lim; i += 1024)
        atomicAdd(&h[dst[base + i] >> LOG_NPBK], 1);
    __syncthreads();
    for (int b = threadIdx.x; b < K; b += 1024) {
        int c = h[b];
        cnt[b * NBLK + blockIdx.x] = c;
        if (c) atomicAdd(&ccount[b], c);
    }
}

__global__ void __launch_bounds__(1024) coarse_scan_kernel(
        const int* __restrict__ ccount, int* __restrict__ cbase,
        int* __restrict__ offsets, int* __restrict__ spill_cursor,
        int K, int N, int E) {
    __shared__ int sc[1024];
    int t = threadIdx.x;
    int v = (t < K) ? ccount[t] : 0;
    sc[t] = v;
    __syncthreads();
    for (int off = 1; off < 1024; off <<= 1) {
        int w = (t >= off) ? sc[t - off] : 0;
        __syncthreads();
        sc[t] += w;
        __syncthreads();
    }
    if (t < K) cbase[t] = sc[t] - v;
    if (t == 0) { cbase[K] = E; offsets[N] = E; *spill_cursor = 0; }
}

__global__ void __launch_bounds__(NBLK) chunk_base_kernel(
        const int* __restrict__ cnt, const int* __restrict__ cbase,
        int* __restrict__ base_tab) {
    __shared__ int sc[NBLK];
    int b = blockIdx.x;
    int t = threadIdx.x;
    int v = cnt[b * NBLK + t];
    sc[t] = v;
    __syncthreads();
    for (int off = 1; off < NBLK; off <<= 1) {
        int w = (t >= off) ? sc[t - off] : 0;
        __syncthreads();
        sc[t] += w;
        __syncthreads();
    }
    base_tab[b * NBLK + t] = cbase[b] + sc[t] - v;
}

__global__ void __launch_bounds__(1024) coarse_scatter_kernel(
        const int* __restrict__ dst, const int* __restrict__ src,
        const float4* __restrict__ sh, const int* __restrict__ base_tab,
        uint2* __restrict__ pay8, int* __restrict__ packed,
        int E, int K, int EPB) {
    __shared__ int cur[MAXK];
    for (int b = threadIdx.x; b < K; b += 1024)
        cur[b] = base_tab[b * NBLK + blockIdx.x];
    __syncthreads();
    int base = blockIdx.x * EPB;
    int lim = min(EPB, E - base);
    for (int i = threadIdx.x; i < lim; i += 1024) {
        int e = base + i;
        int d = dst[e];
        int b = d >> LOG_NPBK;
        int pos = atomicAdd(&cur[b], 1);
        float4 s4 = sh[e];
        pay8[pos] = make_uint2(f2bf(s4.x) | (f2bf(s4.y) << 16),
                               f2bf(s4.z) | (f2bf(s4.w) << 16));
        packed[pos] = ((d & (NPBK - 1)) << 24) | src[e];
    }
}

__global__ void __launch_bounds__(512) fine_sort_kernel(
        const int* __restrict__ cbase, int* __restrict__ offsets,
        uint2* __restrict__ pay8, int* __restrict__ packed,
        uint2* __restrict__ spill_pay, int* __restrict__ spill_pk,
        int* __restrict__ spill_cursor, int N) {
    __shared__ uint2 spay[CAP];
    __shared__ int   spk[CAP];
    __shared__ int   cnt_[NPBK];
    __shared__ int   sc[NPBK];
    __shared__ int   sbase_s;
    int b = blockIdx.x;
    int t = threadIdx.x;
    int cbeg = cbase[b], cend = cbase[b + 1];
    int cnt = cend - cbeg;
    if (t == 0) sbase_s = (cnt > CAP) ? atomicAdd(spill_cursor, cnt - CAP) : 0;
    if (t < NPBK) cnt_[t] = 0;
    __syncthreads();
    for (int i = t; i < cnt; i += 512) {
        int pk = packed[cbeg + i];
        uint2 p8 = pay8[cbeg + i];
        atomicAdd(&cnt_[(pk >> 24) & (NPBK - 1)], 1);
        if (i < CAP) { spk[i] = pk; spay[i] = p8; }
        else {
            int sp = sbase_s + (i - CAP);
            if (sp < SPILL_E) { spill_pk[sp] = pk; spill_pay[sp] = p8; }
        }
    }
    __syncthreads();
    int v = (t < NPBK) ? cnt_[t] : 0;
    if (t < NPBK) sc[t] = v;
    __syncthreads();
    for (int off = 1; off < NPBK; off <<= 1) {
        int w = (t < NPBK && t >= off) ? sc[t - off] : 0;
        __syncthreads();
        if (t < NPBK) sc[t] += w;
        __syncthreads();
    }
    if (t < NPBK) {
        int ex = sc[t] - v;
        int node = (b << LOG_NPBK) + t;
        if (node <= N) offsets[node] = cbeg + ex;
        cnt_[t] = ex;
    }
    __syncthreads();
    for (int i = t; i < cnt; i += 512) {
        int pk; uint2 p8;
        bool ok = true;
        if (i < CAP) { pk = spk[i]; p8 = spay[i]; }
        else {
            int sp = sbase_s + (i - CAP);
            ok = (sp < SPILL_E);
            if (ok) { pk = spill_pk[sp]; p8 = spill_pay[sp]; }
        }
        if (ok) {
            int pos = cbeg + atomicAdd(&cnt_[(pk >> 24) & (NPBK - 1)], 1);
            packed[pos] = pk;
            pay8[pos] = p8;
        }
    }
}

// --- Fallback tiers 3/4 ---
constexpr int SCAN_BLOCK = 256;
constexpr int SCAN_ITEMS = 8;
constexpr int SCAN_CHUNK = SCAN_BLOCK * SCAN_ITEMS;

__global__ void __launch_bounds__(256) hist_kernel(
        const int* __restrict__ dst, int* __restrict__ counts, int E) {
    int e = blockIdx.x * blockDim.x + threadIdx.x;
    if (e < E) atomicAdd(&counts[dst[e]], 1);
}
__global__ void __launch_bounds__(SCAN_BLOCK) block_sum_kernel(
        const int* __restrict__ counts, int* __restrict__ bsums, int N) {
    __shared__ int sdata[SCAN_BLOCK];
    int base = blockIdx.x * SCAN_CHUNK;
    int sum = 0;
    for (int j = 0; j < SCAN_ITEMS; ++j) {
        int idx = base + j * SCAN_BLOCK + threadIdx.x;
        if (idx < N) sum += counts[idx];
    }
    sdata[threadIdx.x] = sum;
    __syncthreads();
    for (int off = SCAN_BLOCK / 2; off > 0; off >>= 1) {
        if (threadIdx.x < off) sdata[threadIdx.x] += sdata[threadIdx.x + off];
        __syncthreads();
    }
    if (threadIdx.x == 0) bsums[blockIdx.x] = sdata[0];
}
__global__ void scan_bsums_kernel(int* __restrict__ bsums, int nb) {
    if (threadIdx.x == 0 && blockIdx.x == 0) {
        int acc = 0;
        for (int i = 0; i < nb; ++i) { int v = bsums[i]; bsums[i] = acc; acc += v; }
    }
}
__global__ void __launch_bounds__(SCAN_BLOCK) scan_final_kernel(
        const int* __restrict__ counts, const int* __restrict__ bsums,
        int* __restrict__ offsets, int* __restrict__ cursors, int N, int E) {
    __shared__ int sdata[SCAN_BLOCK];
    int base = blockIdx.x * SCAN_CHUNK + threadIdx.x * SCAN_ITEMS;
    int local[SCAN_ITEMS];
    int tsum = 0;
    for (int j = 0; j < SCAN_ITEMS; ++j) {
        int idx = base + j;
        int v = (idx < N) ? counts[idx] : 0;
        local[j] = tsum;
        tsum += v;
    }
    sdata[threadIdx.x] = tsum;
    __syncthreads();
    for (int off = 1; off < SCAN_BLOCK; off <<= 1) {
        int v = (threadIdx.x >= off) ? sdata[threadIdx.x - off] : 0;
        __syncthreads();
        sdata[threadIdx.x] += v;
        __syncthreads();
    }
    int excl = sdata[threadIdx.x] - tsum + bsums[blockIdx.x];
    for (int j = 0; j < SCAN_ITEMS; ++j) {
        int idx = base + j;
        if (idx < N) { int o = excl + local[j]; offsets[idx] = o; cursors[idx] = o; }
    }
    if (blockIdx.x == 0 && threadIdx.x == 0) offsets[N] = E;
}
__global__ void __launch_bounds__(256) scatter_ids_kernel(
        const int* __restrict__ dst, int* __restrict__ cursors,
        int* __restrict__ eids, int E) {
    int e = blockIdx.x * blockDim.x + threadIdx.x;
    if (e < E) { int pos = atomicAdd(&cursors[dst[e]], 1); eids[pos] = e; }
}
__global__ void __launch_bounds__(US) accum_ids_kernel(
        const float* __restrict__ x, const float* __restrict__ sh,
        const int* __restrict__ src, const int* __restrict__ offsets,
        const int* __restrict__ eids, float* __restrict__ out) {
    int n = blockIdx.x;
    int t = threadIdx.x;
    int u = t >> 2, s = t & 3;
    int beg = offsets[n], end = offsets[n + 1];
    float acc = 0.f;
    for (int i = beg; i < end; ++i) {
        int e = eids[i];
        acc += x[src[e] * U_DIM + u] * sh[e * 4 + s];
    }
    out[(size_t)n * US + t] = acc;
}
__global__ void __launch_bounds__(US) atomic_kernel(
        const float* __restrict__ x, const float* __restrict__ sh,
        const int* __restrict__ src, const int* __restrict__ dst,
        float* __restrict__ out, int E) {
    int e = blockIdx.x;
    int t = threadIdx.x;
    float v = x[src[e] * U_DIM + (t >> 2)] * sh[e * 4 + (t & 3)];
    atomicAdd(&out[(size_t)dst[e] * US + t], v);
}

extern "C" void kernel_launch(void* const* d_in, const int* in_sizes, int n_in,
                              void* d_out, int out_size, void* d_ws, size_t ws_size,
                              hipStream_t stream) {
    const float* x  = (const float*)d_in[0];
    const float* sh = (const float*)d_in[1];
    const int* src  = (const int*)d_in[2];
    const int* dst  = (const int*)d_in[3];
    float* out = (float*)d_out;

    const int E = in_sizes[2];
    const int N = in_sizes[0] / U_DIM;
    const int xn4 = in_sizes[0] / 4;
    const int egrid = (E + 255) / 256;
    const int nb = (N + SCAN_CHUNK - 1) / SCAN_CHUNK;

    const int K1 = (N + C1_NPB - 1) >> C1_LOG;
    const int KF = (N + FINE_NPB - 1) >> FINE_LOG;
    const int EPB1 = (E + C1_NBLK - 1) / C1_NBLK;
    size_t need_main = (size_t)E * 24 + (size_t)in_sizes[0] * 2 +
                       (size_t)(N + 1 + 2 * KF + 2 + K1 + 1 +
                                2 * K1 * C1_NBLK) * 4;

    const int K = (N + NPBK - 1) >> LOG_NPBK;
    const int EPB = (E + NBLK - 1) / NBLK;
    size_t need_r7 = (size_t)E * 12 + (size_t)SPILL_E * 12 + (size_t)(N + 1) * 4 +
                     (size_t)(2 * K + 2) * 4 + (size_t)(2 * K * NBLK) * 4 +
                     (size_t)in_sizes[0] * 2;
    size_t need_ids = (size_t)E * 4 + (size_t)(3 * N + 1 + nb) * 4;

    if (K1 <= C1_MAXK && KF <= KF_MAX && N <= (1 << 21) &&
        (in_sizes[0] % 4 == 0) && ws_size >= need_main) {
        uint2* pay8A   = (uint2*)d_ws;
        uint2* pay8B   = pay8A + E;
        int* packedA   = (int*)(pay8B + E);
        int* packedB   = packedA + E;
        unsigned short* xb = (unsigned short*)(packedB + E);
        int* offsets   = (int*)(xb + in_sizes[0]);
        int* ccount_f  = offsets + N + 1;
        int* fbase     = ccount_f + KF;
        int* cbase     = fbase + KF + 1;
        int* cnt       = cbase + K1 + 1;
        int* base_tab  = cnt + K1 * C1_NBLK;

        hipMemsetAsync(ccount_f, 0, sizeof(int) * (size_t)KF, stream);
        xcvt_kernel<<<(xn4 + 255) / 256, 256, 0, stream>>>(
            (const float4*)x, (ushort4*)xb, xn4);
        c1_hist_kernel<<<C1_NBLK, 1024, 0, stream>>>(dst, ccount_f, cnt,
                                                     E, KF, K1, EPB1);
        c1_scan_kernel<<<1, 1024, 0, stream>>>(ccount_f, fbase, cbase, offsets,
                                               KF, K1, N, E);
        c1_cbase_kernel<<<K1, C1_NBLK, 0, stream>>>(cnt, cbase, base_tab);
        c1_scatter_kernel<<<C1_NBLK, 1024, 0, stream>>>(dst, src, (const float4*)sh,
                                                        base_tab, pay8A, packedA,
                                                        E, K1, EPB1);
        c2_sort_kernel<<<KF, 512, 0, stream>>>(cbase, fbase, offsets,
                                               pay8A, packedA, pay8B, packedB, N);
        accum_kernel<<<(N + 3) / 4, 256, 0, stream>>>(xb, pay8B, packedB,
                                                      offsets, out, 0x1FFFFF, N);
    } else if (K <= MAXK && (in_sizes[0] % 4 == 0) && ws_size >= need_r7) {
        uint2* pay8      = (uint2*)d_ws;
        uint2* spill_pay = pay8 + E;
        int* packed      = (int*)(spill_pay + SPILL_E);
        int* spill_pk    = packed + E;
        int* offsets     = spill_pk + SPILL_E;
        int* ccount      = offsets + N + 1;
        int* cbase       = ccount + K;
        int* cnt         = cbase + K + 1;
        int* base_tab    = cnt + K * NBLK;
        int* spill_cur   = base_tab + K * NBLK;
        unsigned short* xb = (unsigned short*)(spill_cur + 1);

        hipMemsetAsync(ccount, 0, sizeof(int) * (size_t)K, stream);
        xcvt_kernel<<<(xn4 + 255) / 256, 256, 0, stream>>>(
            (const float4*)x, (ushort4*)xb, xn4);
        coarse_hist_kernel<<<NBLK, 1024, 0, stream>>>(dst, ccount, cnt, E, K, EPB);
        coarse_scan_kernel<<<1, 1024, 0, stream>>>(ccount, cbase, offsets,
                                                   spill_cur, K, N, E);
        chunk_base_kernel<<<K, NBLK, 0, stream>>>(cnt, cbase, base_tab);
        coarse_scatter_kernel<<<NBLK, 1024, 0, stream>>>(dst, src, (const float4*)sh,
                                                         base_tab, pay8, packed,
                                                         E, K, EPB);
        fine_sort_kernel<<<K, 512, 0, stream>>>(cbase, offsets, pay8, packed,
                                                spill_pay, spill_pk, spill_cur, N);
        accum_kernel<<<(N + 3) / 4, 256, 0, stream>>>(xb, pay8, packed,
                                                      offsets, out, 0xFFFFFF, N);
    } else if (ws_size >= need_ids) {
        int* eids    = (int*)d_ws;
        int* counts  = eids + E;
        int* offsets = counts + N;
        int* cursors = offsets + N + 1;
        int* bsums   = cursors + N;

        hipMemsetAsync(counts, 0, sizeof(int) * (size_t)N, stream);
        hist_kernel<<<egrid, 256, 0, stream>>>(dst, counts, E);
        block_sum_kernel<<<nb, SCAN_BLOCK, 0, stream>>>(counts, bsums, N);
        scan_bsums_kernel<<<1, 64, 0, stream>>>(bsums, nb);
        scan_final_kernel<<<nb, SCAN_BLOCK, 0, stream>>>(counts, bsums, offsets, cursors, N, E);
        scatter_ids_kernel<<<egrid, 256, 0, stream>>>(dst, cursors, eids, E);
        accum_ids_kernel<<<N, US, 0, stream>>>(x, sh, src, offsets, eids, out);
    } else {
        hipMemsetAsync(out, 0, sizeof(float) * (size_t)out_size, stream);
        atomic_kernel<<<E, US, 0, stream>>>(x, sh, src, dst, out, E);
    }
}

// Round 16
// 201.658 us; speedup vs baseline: 1.4009x; 1.1180x over previous
//
#include <hip/hip_runtime.h>

// out[n, u*4+s] = sum_{e: dst[e]==n} x[src[e], u] * sh[e, s]
// N=100000, U=32, S=4, E=3200000.
//
// Ledger of lessons:
//  R2: bulk LDS float atomics = ~1 lane/cycle serial floor -> register accum.
//  R4/R5/R7: scattered writes into >~400 streams/block = 4.3x HBM write amp.
//  R8: few deep-serial blocks (17% occ) lose to 100k shallow blocks.
//  R9/R13: xb (6.4MB) is L3-resident; accum FETCH is L2-fill, NOT HBM-bound.
//  R10: NT loads on broadcast/shared streams re-fetch lines (FETCH +11MB).
//  R11: contiguous per-lane ranges + 4 independent gathers in flight.
//  R12: lane-widening + CROSS-LANE REDUCTION = loss (48 shfl swamps short loop).
//  R13: c2 XCD-swizzle bet on undefined block->XCD mapping: -14us. Reverted.
//  R14: pk-fma neutral -> not FMA-throughput-bound.
//  R15: one wave/node, no barriers: 99->87us.
// R16: accum = 16 lanes/edge via ushort2 x-load, 4 NODES PER WAVE (grp=lane>>4
//      owns a node) -> zero reduction, 4 edges retired per wave-slot, 4x fewer
//      gather instructions. R12's widening without R12's reduction cost.

#define U_DIM 32
#define US 128

__device__ inline unsigned f2bf(float f) {          // RNE float->bf16 bits
    unsigned u = __float_as_uint(f);
    return (u + 0x7FFF + ((u >> 16) & 1)) >> 16;
}
__device__ inline float bfl(unsigned w) { return __uint_as_float(w << 16); }
__device__ inline float bfh(unsigned w) { return __uint_as_float(w & 0xFFFF0000u); }

__global__ void __launch_bounds__(256) xcvt_kernel(
        const float4* __restrict__ x4, ushort4* __restrict__ xb4, int n4) {
    int i = blockIdx.x * 256 + threadIdx.x;
    if (i < n4) {
        float4 v = x4[i];
        ushort4 r;
        r.x = (unsigned short)f2bf(v.x);
        r.y = (unsigned short)f2bf(v.y);
        r.z = (unsigned short)f2bf(v.z);
        r.w = (unsigned short)f2bf(v.w);
        xb4[i] = r;
    }
}

// =================== PRIMARY PATH ===================
#define C1_LOG 9
#define C1_NPB 512
#define C1_MAXK 256
#define C1_NBLK 256
#define FINE_LOG 7
#define FINE_NPB 128
#define KF_MAX 1024
#define SCAP 5120             // LDS-staged edges per fine bucket (mean 4082)

// Fine-granularity (128-node) histogram; also per-chunk coarse counts.
__global__ void __launch_bounds__(1024) c1_hist_kernel(
        const int* __restrict__ dst, int* __restrict__ ccount_f,
        int* __restrict__ cnt, int E, int KF, int K1, int EPB) {
    __shared__ int h[KF_MAX];
    for (int b = threadIdx.x; b < KF; b += 1024) h[b] = 0;
    __syncthreads();
    int base = blockIdx.x * EPB;
    int lim = min(EPB, E - base);
    for (int i = threadIdx.x; i < lim; i += 1024)
        atomicAdd(&h[dst[base + i] >> FINE_LOG], 1);
    __syncthreads();
    for (int b = threadIdx.x; b < KF; b += 1024) {
        int c = h[b];
        if (c) atomicAdd(&ccount_f[b], c);
    }
    for (int b = threadIdx.x; b < K1; b += 1024) {
        int c = 0;
        #pragma unroll
        for (int k = 0; k < 4; ++k) {
            int f = 4 * b + k;
            if (f < KF) c += h[f];
        }
        cnt[b * C1_NBLK + blockIdx.x] = c;
    }
}

// One scan over KF fine counts -> fbase; cbase derived; offsets[N]=E.
__global__ void __launch_bounds__(1024) c1_scan_kernel(
        const int* __restrict__ ccount_f, int* __restrict__ fbase,
        int* __restrict__ cbase, int* __restrict__ offsets,
        int KF, int K1, int N, int E) {
    __shared__ int sc[1024];
    int t = threadIdx.x;
    int v = (t < KF) ? ccount_f[t] : 0;
    sc[t] = v;
    __syncthreads();
    for (int off = 1; off < 1024; off <<= 1) {
        int w = (t >= off) ? sc[t - off] : 0;
        __syncthreads();
        sc[t] += w;
        __syncthreads();
    }
    if (t < KF) fbase[t] = sc[t] - v;
    __syncthreads();
    if (t < K1) {
        int f = 4 * t;
        cbase[t] = (f < KF) ? (sc[f] - ccount_f[f]) : E;
    }
    if (t == 0) { fbase[KF] = E; cbase[K1] = E; offsets[N] = E; }
}

__global__ void __launch_bounds__(C1_NBLK) c1_cbase_kernel(
        const int* __restrict__ cnt, const int* __restrict__ cbase,
        int* __restrict__ base_tab) {
    __shared__ int sc[C1_NBLK];
    int b = blockIdx.x;
    int t = threadIdx.x;
    int v = cnt[b * C1_NBLK + t];
    sc[t] = v;
    __syncthreads();
    for (int off = 1; off < C1_NBLK; off <<= 1) {
        int w = (t >= off) ? sc[t - off] : 0;
        __syncthreads();
        sc[t] += w;
        __syncthreads();
    }
    base_tab[b * C1_NBLK + t] = cbase[b] + sc[t] - v;
}

__global__ void __launch_bounds__(1024) c1_scatter_kernel(
        const int* __restrict__ dst, const int* __restrict__ src,
        const float4* __restrict__ sh, const int* __restrict__ base_tab,
        uint2* __restrict__ pay8A, int* __restrict__ packedA,
        int E, int K1, int EPB) {
    __shared__ int cur[C1_MAXK];
    for (int b = threadIdx.x; b < K1; b += 1024)
        cur[b] = base_tab[b * C1_NBLK + blockIdx.x];
    __syncthreads();
    int base = blockIdx.x * EPB;
    int lim = min(EPB, E - base);
    for (int i = threadIdx.x; i < lim; i += 1024) {
        int e = base + i;
        int d = dst[e];
        int b = d >> C1_LOG;
        int pos = atomicAdd(&cur[b], 1);
        float4 s4 = sh[e];
        pay8A[pos] = make_uint2(f2bf(s4.x) | (f2bf(s4.y) << 16),
                                f2bf(s4.z) | (f2bf(s4.w) << 16));
        packedA[pos] = ((d & (C1_NPB - 1)) << 21) | src[e];
    }
}

// One block per fine bucket: stream parent coarse range (L2/L3-shared with 3
// sibling blocks), filter own sub-bucket, LDS-stage in sorted order, then
// DENSE coalesced write-out to B. Emits offsets[]. (R11-proven form.)
__global__ void __launch_bounds__(512) c2_sort_kernel(
        const int* __restrict__ cbase, const int* __restrict__ fbase,
        int* __restrict__ offsets, const uint2* __restrict__ pay8A,
        const int* __restrict__ packedA, uint2* __restrict__ pay8B,
        int* __restrict__ packedB, int N) {
    __shared__ uint2 spay[SCAP];          // 40 KB
    __shared__ int   spk[SCAP];           // 20 KB
    __shared__ int   hh[FINE_NPB];
    __shared__ int   scur[FINE_NPB];
    int fb = blockIdx.x;
    int t = threadIdx.x;
    int parent = fb >> 2, sub = fb & 3;
    int cbeg = cbase[parent], cend = cbase[parent + 1];
    int fbeg = fbase[fb];
    int cnt = fbase[fb + 1] - fbeg;
    if (t < FINE_NPB) hh[t] = 0;
    __syncthreads();
    for (int i = cbeg + t; i < cend; i += 512) {
        int nc = (packedA[i] >> 21) & (C1_NPB - 1);
        if ((nc >> FINE_LOG) == sub)
            atomicAdd(&hh[nc & (FINE_NPB - 1)], 1);
    }
    __syncthreads();
    int v = (t < FINE_NPB) ? hh[t] : 0;
    if (t < FINE_NPB) hh[t] = v;
    __syncthreads();
    for (int off = 1; off < FINE_NPB; off <<= 1) {
        int w = (t < FINE_NPB && t >= off) ? hh[t - off] : 0;
        __syncthreads();
        if (t < FINE_NPB) hh[t] += w;
        __syncthreads();
    }
    if (t < FINE_NPB) {
        int excl = hh[t] - v;
        scur[t] = excl;
        int node = (fb << FINE_LOG) + t;
        if (node < N) offsets[node] = fbeg + excl;
    }
    __syncthreads();
    for (int i = cbeg + t; i < cend; i += 512) {
        int pk = packedA[i];
        int nc = (pk >> 21) & (C1_NPB - 1);
        if ((nc >> FINE_LOG) == sub) {
            int pos = atomicAdd(&scur[nc & (FINE_NPB - 1)], 1);
            uint2 p8 = pay8A[i];
            if (pos < SCAP) { spk[pos] = pk; spay[pos] = p8; }
            else { packedB[fbeg + pos] = pk; pay8B[fbeg + pos] = p8; }
        }
    }
    __syncthreads();
    int lim = min(cnt, SCAP);
    for (int i = t; i < lim; i += 512) {
        packedB[fbeg + i] = spk[i];
        pay8B[fbeg + i] = spay[i];
    }
}

// R16 accum: 256-thr block = 4 waves; each wave handles 4 nodes (grp=lane>>4).
// Lane l=lane&15 covers u={2l,2l+1} via one ushort2 x-load. Per edge: 16-lane
// group broadcast-loads payload, 8 FMAs into a[8]. NO reduction, NO LDS:
// each lane stores its 8 contiguous output floats directly. Unroll-4 MLP.
__global__ void __launch_bounds__(256) accum_kernel(
        const unsigned short* __restrict__ xb, const uint2* __restrict__ pay8,
        const int* __restrict__ packed, const int* __restrict__ offsets,
        float* __restrict__ out, int smask, int N) {
    int wave = threadIdx.x >> 6;
    int lane = threadIdx.x & 63;
    int grp = lane >> 4;              // node within wave
    int l = lane & 15;                // covers u = 2l, 2l+1
    int n = blockIdx.x * 16 + wave * 4 + grp;
    if (n >= N) return;
    int beg = offsets[n], end = offsets[n + 1];
    int u2 = l << 1;
    float a0 = 0.f, a1 = 0.f, a2 = 0.f, a3 = 0.f;
    float a4 = 0.f, a5 = 0.f, a6 = 0.f, a7 = 0.f;
    int i = beg;
    for (; i + 3 < end; i += 4) {
        int pk0 = packed[i], pk1 = packed[i + 1];
        int pk2 = packed[i + 2], pk3 = packed[i + 3];
        uint2 q0 = pay8[i], q1 = pay8[i + 1];
        uint2 q2 = pay8[i + 2], q3 = pay8[i + 3];
        ushort2 xv0 = *reinterpret_cast<const ushort2*>(
            &xb[(size_t)(pk0 & smask) * U_DIM + u2]);
        ushort2 xv1 = *reinterpret_cast<const ushort2*>(
            &xb[(size_t)(pk1 & smask) * U_DIM + u2]);
        ushort2 xv2 = *reinterpret_cast<const ushort2*>(
            &xb[(size_t)(pk2 & smask) * U_DIM + u2]);
        ushort2 xv3 = *reinterpret_cast<const ushort2*>(
            &xb[(size_t)(pk3 & smask) * U_DIM + u2]);
        {
            float xa = bfl((unsigned)xv0.x), xc = bfl((unsigned)xv0.y);
            float s0 = bfl(q0.x), s1 = bfh(q0.x), s2 = bfl(q0.y), s3 = bfh(q0.y);
            a0 += xa * s0; a1 += xa * s1; a2 += xa * s2; a3 += xa * s3;
            a4 += xc * s0; a5 += xc * s1; a6 += xc * s2; a7 += xc * s3;
        }
        {
            float xa = bfl((unsigned)xv1.x), xc = bfl((unsigned)xv1.y);
            float s0 = bfl(q1.x), s1 = bfh(q1.x), s2 = bfl(q1.y), s3 = bfh(q1.y);
            a0 += xa * s0; a1 += xa * s1; a2 += xa * s2; a3 += xa * s3;
            a4 += xc * s0; a5 += xc * s1; a6 += xc * s2; a7 += xc * s3;
        }
        {
            float xa = bfl((unsigned)xv2.x), xc = bfl((unsigned)xv2.y);
            float s0 = bfl(q2.x), s1 = bfh(q2.x), s2 = bfl(q2.y), s3 = bfh(q2.y);
            a0 += xa * s0; a1 += xa * s1; a2 += xa * s2; a3 += xa * s3;
            a4 += xc * s0; a5 += xc * s1; a6 += xc * s2; a7 += xc * s3;
        }
        {
            float xa = bfl((unsigned)xv3.x), xc = bfl((unsigned)xv3.y);
            float s0 = bfl(q3.x), s1 = bfh(q3.x), s2 = bfl(q3.y), s3 = bfh(q3.y);
            a0 += xa * s0; a1 += xa * s1; a2 += xa * s2; a3 += xa * s3;
            a4 += xc * s0; a5 += xc * s1; a6 += xc * s2; a7 += xc * s3;
        }
    }
    for (; i < end; ++i) {
        int pk = packed[i];
        uint2 q = pay8[i];
        ushort2 xv = *reinterpret_cast<const ushort2*>(
            &xb[(size_t)(pk & smask) * U_DIM + u2]);
        float xa = bfl((unsigned)xv.x), xc = bfl((unsigned)xv.y);
        float s0 = bfl(q.x), s1 = bfh(q.x), s2 = bfl(q.y), s3 = bfh(q.y);
        a0 += xa * s0; a1 += xa * s1; a2 += xa * s2; a3 += xa * s3;
        a4 += xc * s0; a5 += xc * s1; a6 += xc * s2; a7 += xc * s3;
    }
    size_t obase = (size_t)n * US + (size_t)u2 * 4;
    *reinterpret_cast<float4*>(&out[obase])     = make_float4(a0, a1, a2, a3);
    *reinterpret_cast<float4*>(&out[obase + 4]) = make_float4(a4, a5, a6, a7);
}

// =================== TIER-2: proven R7 path ===================
#define LOG_NPBK 7
#define NPBK 128
#define MAXK 1024
#define NBLK 256
#define CAP 5120
#define SPILL_E 1000000

__global__ void __launch_bounds__(1024) coarse_hist_kernel(
        const int* __restrict__ dst, int* __restrict__ ccount,
        int* __restrict__ cnt, int E, int K, int EPB) {
    __shared__ int h[MAXK];
    for (int b = threadIdx.x; b < K; b += 1024) h[b] = 0;
    __syncthreads();
    int base = blockIdx.x * EPB;
    int lim = min(EPB, E - base);
    for (int i = threadIdx.x; i < lim; i += 1024)
        atomicAdd(&h[dst[base + i] >> LOG_NPBK], 1);
    __syncthreads();
    for (int b = threadIdx.x; b < K; b += 1024) {
        int c = h[b];
        cnt[b * NBLK + blockIdx.x] = c;
        if (c) atomicAdd(&ccount[b], c);
    }
}

__global__ void __launch_bounds__(1024) coarse_scan_kernel(
        const int* __restrict__ ccount, int* __restrict__ cbase,
        int* __restrict__ offsets, int* __restrict__ spill_cursor,
        int K, int N, int E) {
    __shared__ int sc[1024];
    int t = threadIdx.x;
    int v = (t < K) ? ccount[t] : 0;
    sc[t] = v;
    __syncthreads();
    for (int off = 1; off < 1024; off <<= 1) {
        int w = (t >= off) ? sc[t - off] : 0;
        __syncthreads();
        sc[t] += w;
        __syncthreads();
    }
    if (t < K) cbase[t] = sc[t] - v;
    if (t == 0) { cbase[K] = E; offsets[N] = E; *spill_cursor = 0; }
}

__global__ void __launch_bounds__(NBLK) chunk_base_kernel(
        const int* __restrict__ cnt, const int* __restrict__ cbase,
        int* __restrict__ base_tab) {
    __shared__ int sc[NBLK];
    int b = blockIdx.x;
    int t = threadIdx.x;
    int v = cnt[b * NBLK + t];
    sc[t] = v;
    __syncthreads();
    for (int off = 1; off < NBLK; off <<= 1) {
        int w = (t >= off) ? sc[t - off] : 0;
        __syncthreads();
        sc[t] += w;
        __syncthreads();
    }
    base_tab[b * NBLK + t] = cbase[b] + sc[t] - v;
}

__global__ void __launch_bounds__(1024) coarse_scatter_kernel(
        const int* __restrict__ dst, const int* __restrict__ src,
        const float4* __restrict__ sh, const int* __restrict__ base_tab,
        uint2* __restrict__ pay8, int* __restrict__ packed,
        int E, int K, int EPB) {
    __shared__ int cur[MAXK];
    for (int b = threadIdx.x; b < K; b += 1024)
        cur[b] = base_tab[b * NBLK + blockIdx.x];
    __syncthreads();
    int base = blockIdx.x * EPB;
    int lim = min(EPB, E - base);
    for (int i = threadIdx.x; i < lim; i += 1024) {
        int e = base + i;
        int d = dst[e];
        int b = d >> LOG_NPBK;
        int pos = atomicAdd(&cur[b], 1);
        float4 s4 = sh[e];
        pay8[pos] = make_uint2(f2bf(s4.x) | (f2bf(s4.y) << 16),
                               f2bf(s4.z) | (f2bf(s4.w) << 16));
        packed[pos] = ((d & (NPBK - 1)) << 24) | src[e];
    }
}

__global__ void __launch_bounds__(512) fine_sort_kernel(
        const int* __restrict__ cbase, int* __restrict__ offsets,
        uint2* __restrict__ pay8, int* __restrict__ packed,
        uint2* __restrict__ spill_pay, int* __restrict__ spill_pk,
        int* __restrict__ spill_cursor, int N) {
    __shared__ uint2 spay[CAP];
    __shared__ int   spk[CAP];
    __shared__ int   cnt_[NPBK];
    __shared__ int   sc[NPBK];
    __shared__ int   sbase_s;
    int b = blockIdx.x;
    int t = threadIdx.x;
    int cbeg = cbase[b], cend = cbase[b + 1];
    int cnt = cend - cbeg;
    if (t == 0) sbase_s = (cnt > CAP) ? atomicAdd(spill_cursor, cnt - CAP) : 0;
    if (t < NPBK) cnt_[t] = 0;
    __syncthreads();
    for (int i = t; i < cnt; i += 512) {
        int pk = packed[cbeg + i];
        uint2 p8 = pay8[cbeg + i];
        atomicAdd(&cnt_[(pk >> 24) & (NPBK - 1)], 1);
        if (i < CAP) { spk[i] = pk; spay[i] = p8; }
        else {
            int sp = sbase_s + (i - CAP);
            if (sp < SPILL_E) { spill_pk[sp] = pk; spill_pay[sp] = p8; }
        }
    }
    __syncthreads();
    int v = (t < NPBK) ? cnt_[t] : 0;
    if (t < NPBK) sc[t] = v;
    __syncthreads();
    for (int off = 1; off < NPBK; off <<= 1) {
        int w = (t < NPBK && t >= off) ? sc[t - off] : 0;
        __syncthreads();
        if (t < NPBK) sc[t] += w;
        __syncthreads();
    }
    if (t < NPBK) {
        int ex = sc[t] - v;
        int node = (b << LOG_NPBK) + t;
        if (node <= N) offsets[node] = cbeg + ex;
        cnt_[t] = ex;
    }
    __syncthreads();
    for (int i = t; i < cnt; i += 512) {
        int pk; uint2 p8;
        bool ok = true;
        if (i < CAP) { pk = spk[i]; p8 = spay[i]; }
        else {
            int sp = sbase_s + (i - CAP);
            ok = (sp < SPILL_E);
            if (ok) { pk = spill_pk[sp]; p8 = spill_pay[sp]; }
        }
        if (ok) {
            int pos = cbeg + atomicAdd(&cnt_[(pk >> 24) & (NPBK - 1)], 1);
            packed[pos] = pk;
            pay8[pos] = p8;
        }
    }
}

// --- Fallback tiers 3/4 ---
constexpr int SCAN_BLOCK = 256;
constexpr int SCAN_ITEMS = 8;
constexpr int SCAN_CHUNK = SCAN_BLOCK * SCAN_ITEMS;

__global__ void __launch_bounds__(256) hist_kernel(
        const int* __restrict__ dst, int* __restrict__ counts, int E) {
    int e = blockIdx.x * blockDim.x + threadIdx.x;
    if (e < E) atomicAdd(&counts[dst[e]], 1);
}
__global__ void __launch_bounds__(SCAN_BLOCK) block_sum_kernel(
        const int* __restrict__ counts, int* __restrict__ bsums, int N) {
    __shared__ int sdata[SCAN_BLOCK];
    int base = blockIdx.x * SCAN_CHUNK;
    int sum = 0;
    for (int j = 0; j < SCAN_ITEMS; ++j) {
        int idx = base + j * SCAN_BLOCK + threadIdx.x;
        if (idx < N) sum += counts[idx];
    }
    sdata[threadIdx.x] = sum;
    __syncthreads();
    for (int off = SCAN_BLOCK / 2; off > 0; off >>= 1) {
        if (threadIdx.x < off) sdata[threadIdx.x] += sdata[threadIdx.x + off];
        __syncthreads();
    }
    if (threadIdx.x == 0) bsums[blockIdx.x] = sdata[0];
}
__global__ void scan_bsums_kernel(int* __restrict__ bsums, int nb) {
    if (threadIdx.x == 0 && blockIdx.x == 0) {
        int acc = 0;
        for (int i = 0; i < nb; ++i) { int v = bsums[i]; bsums[i] = acc; acc += v; }
    }
}
__global__ void __launch_bounds__(SCAN_BLOCK) scan_final_kernel(
        const int* __restrict__ counts, const int* __restrict__ bsums,
        int* __restrict__ offsets, int* __restrict__ cursors, int N, int E) {
    __shared__ int sdata[SCAN_BLOCK];
    int base = blockIdx.x * SCAN_CHUNK + threadIdx.x * SCAN_ITEMS;
    int local[SCAN_ITEMS];
    int tsum = 0;
    for (int j = 0; j < SCAN_ITEMS; ++j) {
        int idx = base + j;
        int v = (idx < N) ? counts[idx] : 0;
        local[j] = tsum;
        tsum += v;
    }
    sdata[threadIdx.x] = tsum;
    __syncthreads();
    for (int off = 1; off < SCAN_BLOCK; off <<= 1) {
        int v = (threadIdx.x >= off) ? sdata[threadIdx.x - off] : 0;
        __syncthreads();
        sdata[threadIdx.x] += v;
        __syncthreads();
    }
    int excl = sdata[threadIdx.x] - tsum + bsums[blockIdx.x];
    for (int j = 0; j < SCAN_ITEMS; ++j) {
        int idx = base + j;
        if (idx < N) { int o = excl + local[j]; offsets[idx] = o; cursors[idx] = o; }
    }
    if (blockIdx.x == 0 && threadIdx.x == 0) offsets[N] = E;
}
__global__ void __launch_bounds__(256) scatter_ids_kernel(
        const int* __restrict__ dst, int* __restrict__ cursors,
        int* __restrict__ eids, int E) {
    int e = blockIdx.x * blockDim.x + threadIdx.x;
    if (e < E) { int pos = atomicAdd(&cursors[dst[e]], 1); eids[pos] = e; }
}
__global__ void __launch_bounds__(US) accum_ids_kernel(
        const float* __restrict__ x, const float* __restrict__ sh,
        const int* __restrict__ src, const int* __restrict__ offsets,
        const int* __restrict__ eids, float* __restrict__ out) {
    int n = blockIdx.x;
    int t = threadIdx.x;
    int u = t >> 2, s = t & 3;
    int beg = offsets[n], end = offsets[n + 1];
    float acc = 0.f;
    for (int i = beg; i < end; ++i) {
        int e = eids[i];
        acc += x[src[e] * U_DIM + u] * sh[e * 4 + s];
    }
    out[(size_t)n * US + t] = acc;
}
__global__ void __launch_bounds__(US) atomic_kernel(
        const float* __restrict__ x, const float* __restrict__ sh,
        const int* __restrict__ src, const int* __restrict__ dst,
        float* __restrict__ out, int E) {
    int e = blockIdx.x;
    int t = threadIdx.x;
    float v = x[src[e] * U_DIM + (t >> 2)] * sh[e * 4 + (t & 3)];
    atomicAdd(&out[(size_t)dst[e] * US + t], v);
}

extern "C" void kernel_launch(void* const* d_in, const int* in_sizes, int n_in,
                              void* d_out, int out_size, void* d_ws, size_t ws_size,
                              hipStream_t stream) {
    const float* x  = (const float*)d_in[0];
    const float* sh = (const float*)d_in[1];
    const int* src  = (const int*)d_in[2];
    const int* dst  = (const int*)d_in[3];
    float* out = (float*)d_out;

    const int E = in_sizes[2];
    const int N = in_sizes[0] / U_DIM;
    const int xn4 = in_sizes[0] / 4;
    const int egrid = (E + 255) / 256;
    const int nb = (N + SCAN_CHUNK - 1) / SCAN_CHUNK;

    const int K1 = (N + C1_NPB - 1) >> C1_LOG;
    const int KF = (N + FINE_NPB - 1) >> FINE_LOG;
    const int EPB1 = (E + C1_NBLK - 1) / C1_NBLK;
    size_t need_main = (size_t)E * 24 + (size_t)in_sizes[0] * 2 +
                       (size_t)(N + 1 + 2 * KF + 2 + K1 + 1 +
                                2 * K1 * C1_NBLK) * 4;

    const int K = (N + NPBK - 1) >> LOG_NPBK;
    const int EPB = (E + NBLK - 1) / NBLK;
    size_t need_r7 = (size_t)E * 12 + (size_t)SPILL_E * 12 + (size_t)(N + 1) * 4 +
                     (size_t)(2 * K + 2) * 4 + (size_t)(2 * K * NBLK) * 4 +
                     (size_t)in_sizes[0] * 2;
    size_t need_ids = (size_t)E * 4 + (size_t)(3 * N + 1 + nb) * 4;

    if (K1 <= C1_MAXK && KF <= KF_MAX && N <= (1 << 21) &&
        (in_sizes[0] % 4 == 0) && ws_size >= need_main) {
        uint2* pay8A   = (uint2*)d_ws;
        uint2* pay8B   = pay8A + E;
        int* packedA   = (int*)(pay8B + E);
        int* packedB   = packedA + E;
        unsigned short* xb = (unsigned short*)(packedB + E);
        int* offsets   = (int*)(xb + in_sizes[0]);
        int* ccount_f  = offsets + N + 1;
        int* fbase     = ccount_f + KF;
        int* cbase     = fbase + KF + 1;
        int* cnt       = cbase + K1 + 1;
        int* base_tab  = cnt + K1 * C1_NBLK;

        hipMemsetAsync(ccount_f, 0, sizeof(int) * (size_t)KF, stream);
        xcvt_kernel<<<(xn4 + 255) / 256, 256, 0, stream>>>(
            (const float4*)x, (ushort4*)xb, xn4);
        c1_hist_kernel<<<C1_NBLK, 1024, 0, stream>>>(dst, ccount_f, cnt,
                                                     E, KF, K1, EPB1);
        c1_scan_kernel<<<1, 1024, 0, stream>>>(ccount_f, fbase, cbase, offsets,
                                               KF, K1, N, E);
        c1_cbase_kernel<<<K1, C1_NBLK, 0, stream>>>(cnt, cbase, base_tab);
        c1_scatter_kernel<<<C1_NBLK, 1024, 0, stream>>>(dst, src, (const float4*)sh,
                                                        base_tab, pay8A, packedA,
                                                        E, K1, EPB1);
        c2_sort_kernel<<<KF, 512, 0, stream>>>(cbase, fbase, offsets,
                                               pay8A, packedA, pay8B, packedB, N);
        accum_kernel<<<(N + 15) / 16, 256, 0, stream>>>(xb, pay8B, packedB,
                                                        offsets, out, 0x1FFFFF, N);
    } else if (K <= MAXK && (in_sizes[0] % 4 == 0) && ws_size >= need_r7) {
        uint2* pay8      = (uint2*)d_ws;
        uint2* spill_pay = pay8 + E;
        int* packed      = (int*)(spill_pay + SPILL_E);
        int* spill_pk    = packed + E;
        int* offsets     = spill_pk + SPILL_E;
        int* ccount      = offsets + N + 1;
        int* cbase       = ccount + K;
        int* cnt         = cbase + K + 1;
        int* base_tab    = cnt + K * NBLK;
        int* spill_cur   = base_tab + K * NBLK;
        unsigned short* xb = (unsigned short*)(spill_cur + 1);

        hipMemsetAsync(ccount, 0, sizeof(int) * (size_t)K, stream);
        xcvt_kernel<<<(xn4 + 255) / 256, 256, 0, stream>>>(
            (const float4*)x, (ushort4*)xb, xn4);
        coarse_hist_kernel<<<NBLK, 1024, 0, stream>>>(dst, ccount, cnt, E, K, EPB);
        coarse_scan_kernel<<<1, 1024, 0, stream>>>(ccount, cbase, offsets,
                                                   spill_cur, K, N, E);
        chunk_base_kernel<<<K, NBLK, 0, stream>>>(cnt, cbase, base_tab);
        coarse_scatter_kernel<<<NBLK, 1024, 0, stream>>>(dst, src, (const float4*)sh,
                                                         base_tab, pay8, packed,
                                                         E, K, EPB);
        fine_sort_kernel<<<K, 512, 0, stream>>>(cbase, offsets, pay8, packed,
                                                spill_pay, spill_pk, spill_cur, N);
        accum_kernel<<<(N + 15) / 16, 256, 0, stream>>>(xb, pay8, packed,
                                                        offsets, out, 0xFFFFFF, N);
    } else if (ws_size >= need_ids) {
        int* eids    = (int*)d_ws;
        int* counts  = eids + E;
        int* offsets = counts + N;
        int* cursors = offsets + N + 1;
        int* bsums   = cursors + N;

        hipMemsetAsync(counts, 0, sizeof(int) * (size_t)N, stream);
        hist_kernel<<<egrid, 256, 0, stream>>>(dst, counts, E);
        block_sum_kernel<<<nb, SCAN_BLOCK, 0, stream>>>(counts, bsums, N);
        scan_bsums_kernel<<<1, 64, 0, stream>>>(bsums, nb);
        scan_final_kernel<<<nb, SCAN_BLOCK, 0, stream>>>(counts, bsums, offsets, cursors, N, E);
        scatter_ids_kernel<<<egrid, 256, 0, stream>>>(dst, cursors, eids, E);
        accum_ids_kernel<<<N, US, 0, stream>>>(x, sh, src, offsets, eids, out);
    } else {
        hipMemsetAsync(out, 0, sizeof(float) * (size_t)out_size, stream);
        atomic_kernel<<<E, US, 0, stream>>>(x, sh, src, dst, out, E);
    }
}

// Round 17
// 194.490 us; speedup vs baseline: 1.4525x; 1.0369x over previous
//
#include <hip/hip_runtime.h>

// out[n, u*4+s] = sum_{e: dst[e]==n} x[src[e], u] * sh[e, s]
// N=100000, U=32, S=4, E=3200000.
//
// Ledger of lessons:
//  R2: bulk LDS float atomics = ~1 lane/cycle serial floor -> register accum.
//  R4/R5/R7: scattered writes, many streams/block = HBM write amp.
//  R8: few deep-serial blocks (17% occ) lose to 100k shallow blocks.
//  R9/R13: xb/sh are L3-resident across replays; FETCH is L2-fill.
//  R10: NT loads on broadcast/shared streams re-fetch lines.
//  R11/R15/R16: accum: contiguous ranges, 1 wave/node -> 4 nodes/wave,
//      16 lanes/edge, zero reduction: 99->87->~65us.
//  R12: lane-widening + cross-lane reduction = loss.
//  R13: XCD-swizzle bet on undefined block->XCD mapping: reverted.
//  R16 counters: c1_scatter WRITE 96MB vs 38.4 ideal (2.5x) — TEMPORAL:
//      64-edge runs arrive spread over block lifetime, lines evicted partial.
// R17: c1_scatter = subchunk (4096) LDS counting-sort + burst write-out:
//      each line's stores arrive back-to-back (c2_sort's trick, applied to c1).

#define U_DIM 32
#define US 128

__device__ inline unsigned f2bf(float f) {          // RNE float->bf16 bits
    unsigned u = __float_as_uint(f);
    return (u + 0x7FFF + ((u >> 16) & 1)) >> 16;
}
__device__ inline float bfl(unsigned w) { return __uint_as_float(w << 16); }
__device__ inline float bfh(unsigned w) { return __uint_as_float(w & 0xFFFF0000u); }

__global__ void __launch_bounds__(256) xcvt_kernel(
        const float4* __restrict__ x4, ushort4* __restrict__ xb4, int n4) {
    int i = blockIdx.x * 256 + threadIdx.x;
    if (i < n4) {
        float4 v = x4[i];
        ushort4 r;
        r.x = (unsigned short)f2bf(v.x);
        r.y = (unsigned short)f2bf(v.y);
        r.z = (unsigned short)f2bf(v.z);
        r.w = (unsigned short)f2bf(v.w);
        xb4[i] = r;
    }
}

// =================== PRIMARY PATH ===================
#define C1_LOG 9
#define C1_NPB 512
#define C1_MAXK 256
#define C1_NBLK 256
#define FINE_LOG 7
#define FINE_NPB 128
#define KF_MAX 1024
#define SCAP 5120             // LDS-staged edges per fine bucket (mean 4082)
#define SCH 4096              // c1_scatter subchunk (LDS-sorted burst unit)

// Fine-granularity (128-node) histogram; also per-chunk coarse counts.
__global__ void __launch_bounds__(1024) c1_hist_kernel(
        const int* __restrict__ dst, int* __restrict__ ccount_f,
        int* __restrict__ cnt, int E, int KF, int K1, int EPB) {
    __shared__ int h[KF_MAX];
    for (int b = threadIdx.x; b < KF; b += 1024) h[b] = 0;
    __syncthreads();
    int base = blockIdx.x * EPB;
    int lim = min(EPB, E - base);
    for (int i = threadIdx.x; i < lim; i += 1024)
        atomicAdd(&h[dst[base + i] >> FINE_LOG], 1);
    __syncthreads();
    for (int b = threadIdx.x; b < KF; b += 1024) {
        int c = h[b];
        if (c) atomicAdd(&ccount_f[b], c);
    }
    for (int b = threadIdx.x; b < K1; b += 1024) {
        int c = 0;
        #pragma unroll
        for (int k = 0; k < 4; ++k) {
            int f = 4 * b + k;
            if (f < KF) c += h[f];
        }
        cnt[b * C1_NBLK + blockIdx.x] = c;
    }
}

// One scan over KF fine counts -> fbase; cbase derived; offsets[N]=E.
__global__ void __launch_bounds__(1024) c1_scan_kernel(
        const int* __restrict__ ccount_f, int* __restrict__ fbase,
        int* __restrict__ cbase, int* __restrict__ offsets,
        int KF, int K1, int N, int E) {
    __shared__ int sc[1024];
    int t = threadIdx.x;
    int v = (t < KF) ? ccount_f[t] : 0;
    sc[t] = v;
    __syncthreads();
    for (int off = 1; off < 1024; off <<= 1) {
        int w = (t >= off) ? sc[t - off] : 0;
        __syncthreads();
        sc[t] += w;
        __syncthreads();
    }
    if (t < KF) fbase[t] = sc[t] - v;
    __syncthreads();
    if (t < K1) {
        int f = 4 * t;
        cbase[t] = (f < KF) ? (sc[f] - ccount_f[f]) : E;
    }
    if (t == 0) { fbase[KF] = E; cbase[K1] = E; offsets[N] = E; }
}

__global__ void __launch_bounds__(C1_NBLK) c1_cbase_kernel(
        const int* __restrict__ cnt, const int* __restrict__ cbase,
        int* __restrict__ base_tab) {
    __shared__ int sc[C1_NBLK];
    int b = blockIdx.x;
    int t = threadIdx.x;
    int v = cnt[b * C1_NBLK + t];
    sc[t] = v;
    __syncthreads();
    for (int off = 1; off < C1_NBLK; off <<= 1) {
        int w = (t >= off) ? sc[t - off] : 0;
        __syncthreads();
        sc[t] += w;
        __syncthreads();
    }
    base_tab[b * C1_NBLK + t] = cbase[b] + sc[t] - v;
}

// R17: subchunk LDS counting-sort + burst write. Writes for each output line
// arrive back-to-back from consecutive lanes -> L2 write-combining succeeds.
__global__ void __launch_bounds__(1024) c1_scatter_kernel(
        const int* __restrict__ dst, const int* __restrict__ src,
        const float4* __restrict__ sh, const int* __restrict__ base_tab,
        uint2* __restrict__ pay8A, int* __restrict__ packedA,
        int E, int K1, int EPB) {
    __shared__ uint2 spay[SCH];           // 32 KB
    __shared__ int   spk[SCH];            // 16 KB
    __shared__ unsigned char sbkt[SCH];   // 4 KB
    __shared__ int   hist[C1_MAXK];
    __shared__ int   lo[C1_MAXK];
    __shared__ int   scur[C1_MAXK];
    __shared__ int   gcur[C1_MAXK];
    __shared__ int   sc[C1_MAXK];
    int t = threadIdx.x;
    for (int b = t; b < K1; b += 1024)
        gcur[b] = base_tab[b * C1_NBLK + blockIdx.x];
    int base = blockIdx.x * EPB;
    int lim = min(EPB, E - base);

    for (int sb = 0; sb < lim; sb += SCH) {
        int sublen = min(SCH, lim - sb);
        for (int b = t; b < K1; b += 1024) hist[b] = 0;
        __syncthreads();
        // Pass A: stage up to 4 edges/thread in registers, build histogram.
        int bk[4], pk[4];
        uint2 pv[4];
        bool vld[4];
        #pragma unroll
        for (int k = 0; k < 4; ++k) {
            int idx = t + k * 1024;
            vld[k] = (idx < sublen);
            if (vld[k]) {
                int e = base + sb + idx;
                int d = dst[e];
                bk[k] = d >> C1_LOG;
                float4 s4 = sh[e];
                pv[k] = make_uint2(f2bf(s4.x) | (f2bf(s4.y) << 16),
                                   f2bf(s4.z) | (f2bf(s4.w) << 16));
                pk[k] = ((d & (C1_NPB - 1)) << 21) | src[e];
                atomicAdd(&hist[bk[k]], 1);
            }
        }
        __syncthreads();
        // Scan hist (K1 <= 256) with first 256 threads.
        if (t < C1_MAXK) sc[t] = (t < K1) ? hist[t] : 0;
        __syncthreads();
        for (int off = 1; off < C1_MAXK; off <<= 1) {
            int w = 0;
            if (t < C1_MAXK && t >= off) w = sc[t - off];
            __syncthreads();
            if (t < C1_MAXK) sc[t] += w;
            __syncthreads();
        }
        if (t < C1_MAXK) {
            int excl = sc[t] - ((t < K1) ? hist[t] : 0);
            lo[t] = excl;
            scur[t] = excl;
        }
        __syncthreads();
        // Pass B: place into LDS in bucket-sorted order.
        #pragma unroll
        for (int k = 0; k < 4; ++k) {
            if (vld[k]) {
                int pos = atomicAdd(&scur[bk[k]], 1);
                spk[pos] = pk[k];
                spay[pos] = pv[k];
                sbkt[pos] = (unsigned char)bk[k];
            }
        }
        __syncthreads();
        // Burst write-out: consecutive lanes -> consecutive addresses.
        for (int i = t; i < sublen; i += 1024) {
            int b = sbkt[i];
            int gd = gcur[b] + (i - lo[b]);
            packedA[gd] = spk[i];
            pay8A[gd] = spay[i];
        }
        __syncthreads();
        if (t < K1) gcur[t] += hist[t];
        __syncthreads();
    }
}

// One block per fine bucket: stream parent coarse range (L2/L3-shared with 3
// sibling blocks), filter own sub-bucket, LDS-stage in sorted order, then
// DENSE coalesced write-out to B. Emits offsets[]. (R11-proven form.)
__global__ void __launch_bounds__(512) c2_sort_kernel(
        const int* __restrict__ cbase, const int* __restrict__ fbase,
        int* __restrict__ offsets, const uint2* __restrict__ pay8A,
        const int* __restrict__ packedA, uint2* __restrict__ pay8B,
        int* __restrict__ packedB, int N) {
    __shared__ uint2 spay[SCAP];          // 40 KB
    __shared__ int   spk[SCAP];           // 20 KB
    __shared__ int   hh[FINE_NPB];
    __shared__ int   scur[FINE_NPB];
    int fb = blockIdx.x;
    int t = threadIdx.x;
    int parent = fb >> 2, sub = fb & 3;
    int cbeg = cbase[parent], cend = cbase[parent + 1];
    int fbeg = fbase[fb];
    int cnt = fbase[fb + 1] - fbeg;
    if (t < FINE_NPB) hh[t] = 0;
    __syncthreads();
    for (int i = cbeg + t; i < cend; i += 512) {
        int nc = (packedA[i] >> 21) & (C1_NPB - 1);
        if ((nc >> FINE_LOG) == sub)
            atomicAdd(&hh[nc & (FINE_NPB - 1)], 1);
    }
    __syncthreads();
    int v = (t < FINE_NPB) ? hh[t] : 0;
    if (t < FINE_NPB) hh[t] = v;
    __syncthreads();
    for (int off = 1; off < FINE_NPB; off <<= 1) {
        int w = (t < FINE_NPB && t >= off) ? hh[t - off] : 0;
        __syncthreads();
        if (t < FINE_NPB) hh[t] += w;
        __syncthreads();
    }
    if (t < FINE_NPB) {
        int excl = hh[t] - v;
        scur[t] = excl;
        int node = (fb << FINE_LOG) + t;
        if (node < N) offsets[node] = fbeg + excl;
    }
    __syncthreads();
    for (int i = cbeg + t; i < cend; i += 512) {
        int pk = packedA[i];
        int nc = (pk >> 21) & (C1_NPB - 1);
        if ((nc >> FINE_LOG) == sub) {
            int pos = atomicAdd(&scur[nc & (FINE_NPB - 1)], 1);
            uint2 p8 = pay8A[i];
            if (pos < SCAP) { spk[pos] = pk; spay[pos] = p8; }
            else { packedB[fbeg + pos] = pk; pay8B[fbeg + pos] = p8; }
        }
    }
    __syncthreads();
    int lim = min(cnt, SCAP);
    for (int i = t; i < lim; i += 512) {
        packedB[fbeg + i] = spk[i];
        pay8B[fbeg + i] = spay[i];
    }
}

// R16 accum: 256-thr block = 4 waves; each wave handles 4 nodes (grp=lane>>4).
// Lane l=lane&15 covers u={2l,2l+1} via one ushort2 x-load. Per edge: 16-lane
// group broadcast-loads payload, 8 FMAs into a[8]. NO reduction, NO LDS.
__global__ void __launch_bounds__(256) accum_kernel(
        const unsigned short* __restrict__ xb, const uint2* __restrict__ pay8,
        const int* __restrict__ packed, const int* __restrict__ offsets,
        float* __restrict__ out, int smask, int N) {
    int wave = threadIdx.x >> 6;
    int lane = threadIdx.x & 63;
    int grp = lane >> 4;              // node within wave
    int l = lane & 15;                // covers u = 2l, 2l+1
    int n = blockIdx.x * 16 + wave * 4 + grp;
    if (n >= N) return;
    int beg = offsets[n], end = offsets[n + 1];
    int u2 = l << 1;
    float a0 = 0.f, a1 = 0.f, a2 = 0.f, a3 = 0.f;
    float a4 = 0.f, a5 = 0.f, a6 = 0.f, a7 = 0.f;
    int i = beg;
    for (; i + 3 < end; i += 4) {
        int pk0 = packed[i], pk1 = packed[i + 1];
        int pk2 = packed[i + 2], pk3 = packed[i + 3];
        uint2 q0 = pay8[i], q1 = pay8[i + 1];
        uint2 q2 = pay8[i + 2], q3 = pay8[i + 3];
        ushort2 xv0 = *reinterpret_cast<const ushort2*>(
            &xb[(size_t)(pk0 & smask) * U_DIM + u2]);
        ushort2 xv1 = *reinterpret_cast<const ushort2*>(
            &xb[(size_t)(pk1 & smask) * U_DIM + u2]);
        ushort2 xv2 = *reinterpret_cast<const ushort2*>(
            &xb[(size_t)(pk2 & smask) * U_DIM + u2]);
        ushort2 xv3 = *reinterpret_cast<const ushort2*>(
            &xb[(size_t)(pk3 & smask) * U_DIM + u2]);
        {
            float xa = bfl((unsigned)xv0.x), xc = bfl((unsigned)xv0.y);
            float s0 = bfl(q0.x), s1 = bfh(q0.x), s2 = bfl(q0.y), s3 = bfh(q0.y);
            a0 += xa * s0; a1 += xa * s1; a2 += xa * s2; a3 += xa * s3;
            a4 += xc * s0; a5 += xc * s1; a6 += xc * s2; a7 += xc * s3;
        }
        {
            float xa = bfl((unsigned)xv1.x), xc = bfl((unsigned)xv1.y);
            float s0 = bfl(q1.x), s1 = bfh(q1.x), s2 = bfl(q1.y), s3 = bfh(q1.y);
            a0 += xa * s0; a1 += xa * s1; a2 += xa * s2; a3 += xa * s3;
            a4 += xc * s0; a5 += xc * s1; a6 += xc * s2; a7 += xc * s3;
        }
        {
            float xa = bfl((unsigned)xv2.x), xc = bfl((unsigned)xv2.y);
            float s0 = bfl(q2.x), s1 = bfh(q2.x), s2 = bfl(q2.y), s3 = bfh(q2.y);
            a0 += xa * s0; a1 += xa * s1; a2 += xa * s2; a3 += xa * s3;
            a4 += xc * s0; a5 += xc * s1; a6 += xc * s2; a7 += xc * s3;
        }
        {
            float xa = bfl((unsigned)xv3.x), xc = bfl((unsigned)xv3.y);
            float s0 = bfl(q3.x), s1 = bfh(q3.x), s2 = bfl(q3.y), s3 = bfh(q3.y);
            a0 += xa * s0; a1 += xa * s1; a2 += xa * s2; a3 += xa * s3;
            a4 += xc * s0; a5 += xc * s1; a6 += xc * s2; a7 += xc * s3;
        }
    }
    for (; i < end; ++i) {
        int pk = packed[i];
        uint2 q = pay8[i];
        ushort2 xv = *reinterpret_cast<const ushort2*>(
            &xb[(size_t)(pk & smask) * U_DIM + u2]);
        float xa = bfl((unsigned)xv.x), xc = bfl((unsigned)xv.y);
        float s0 = bfl(q.x), s1 = bfh(q.x), s2 = bfl(q.y), s3 = bfh(q.y);
        a0 += xa * s0; a1 += xa * s1; a2 += xa * s2; a3 += xa * s3;
        a4 += xc * s0; a5 += xc * s1; a6 += xc * s2; a7 += xc * s3;
    }
    size_t obase = (size_t)n * US + (size_t)u2 * 4;
    *reinterpret_cast<float4*>(&out[obase])     = make_float4(a0, a1, a2, a3);
    *reinterpret_cast<float4*>(&out[obase + 4]) = make_float4(a4, a5, a6, a7);
}

// =================== TIER-2: proven R7 path ===================
#define LOG_NPBK 7
#define NPBK 128
#define MAXK 1024
#define NBLK 256
#define CAP 5120
#define SPILL_E 1000000

__global__ void __launch_bounds__(1024) coarse_hist_kernel(
        const int* __restrict__ dst, int* __restrict__ ccount,
        int* __restrict__ cnt, int E, int K, int EPB) {
    __shared__ int h[MAXK];
    for (int b = threadIdx.x; b < K; b += 1024) h[b] = 0;
    __syncthreads();
    int base = blockIdx.x * EPB;
    int lim = min(EPB, E - base);
    for (int i = threadIdx.x; i < lim; i += 1024)
        atomicAdd(&h[dst[base + i] >> LOG_NPBK], 1);
    __syncthreads();
    for (int b = threadIdx.x; b < K; b += 1024) {
        int c = h[b];
        cnt[b * NBLK + blockIdx.x] = c;
        if (c) atomicAdd(&ccount[b], c);
    }
}

__global__ void __launch_bounds__(1024) coarse_scan_kernel(
        const int* __restrict__ ccount, int* __restrict__ cbase,
        int* __restrict__ offsets, int* __restrict__ spill_cursor,
        int K, int N, int E) {
    __shared__ int sc[1024];
    int t = threadIdx.x;
    int v = (t < K) ? ccount[t] : 0;
    sc[t] = v;
    __syncthreads();
    for (int off = 1; off < 1024; off <<= 1) {
        int w = (t >= off) ? sc[t - off] : 0;
        __syncthreads();
        sc[t] += w;
        __syncthreads();
    }
    if (t < K) cbase[t] = sc[t] - v;
    if (t == 0) { cbase[K] = E; offsets[N] = E; *spill_cursor = 0; }
}

__global__ void __launch_bounds__(NBLK) chunk_base_kernel(
        const int* __restrict__ cnt, const int* __restrict__ cbase,
        int* __restrict__ base_tab) {
    __shared__ int sc[NBLK];
    int b = blockIdx.x;
    int t = threadIdx.x;
    int v = cnt[b * NBLK + t];
    sc[t] = v;
    __syncthreads();
    for (int off = 1; off < NBLK; off <<= 1) {
        int w = (t >= off) ? sc[t - off] : 0;
        __syncthreads();
        sc[t] += w;
        __syncthreads();
    }
    base_tab[b * NBLK + t] = cbase[b] + sc[t] - v;
}

__global__ void __launch_bounds__(1024) coarse_scatter_kernel(
        const int* __restrict__ dst, const int* __restrict__ src,
        const float4* __restrict__ sh, const int* __restrict__ base_tab,
        uint2* __restrict__ pay8, int* __restrict__ packed,
        int E, int K, int EPB) {
    __shared__ int cur[MAXK];
    for (int b = threadIdx.x; b < K; b += 1024)
        cur[b] = base_tab[b * NBLK + blockIdx.x];
    __syncthreads();
    int base = blockIdx.x * EPB;
    int lim = min(EPB, E - base);
    for (int i = threadIdx.x; i < lim; i += 1024) {
        int e = base + i;
        int d = dst[e];
        int b = d >> LOG_NPBK;
        int pos = atomicAdd(&cur[b], 1);
        float4 s4 = sh[e];
        pay8[pos] = make_uint2(f2bf(s4.x) | (f2bf(s4.y) << 16),
                               f2bf(s4.z) | (f2bf(s4.w) << 16));
        packed[pos] = ((d & (NPBK - 1)) << 24) | src[e];
    }
}

__global__ void __launch_bounds__(512) fine_sort_kernel(
        const int* __restrict__ cbase, int* __restrict__ offsets,
        uint2* __restrict__ pay8, int* __restrict__ packed,
        uint2* __restrict__ spill_pay, int* __restrict__ spill_pk,
        int* __restrict__ spill_cursor, int N) {
    __shared__ uint2 spay[CAP];
    __shared__ int   spk[CAP];
    __shared__ int   cnt_[NPBK];
    __shared__ int   sc[NPBK];
    __shared__ int   sbase_s;
    int b = blockIdx.x;
    int t = threadIdx.x;
    int cbeg = cbase[b], cend = cbase[b + 1];
    int cnt = cend - cbeg;
    if (t == 0) sbase_s = (cnt > CAP) ? atomicAdd(spill_cursor, cnt - CAP) : 0;
    if (t < NPBK) cnt_[t] = 0;
    __syncthreads();
    for (int i = t; i < cnt; i += 512) {
        int pk = packed[cbeg + i];
        uint2 p8 = pay8[cbeg + i];
        atomicAdd(&cnt_[(pk >> 24) & (NPBK - 1)], 1);
        if (i < CAP) { spk[i] = pk; spay[i] = p8; }
        else {
            int sp = sbase_s + (i - CAP);
            if (sp < SPILL_E) { spill_pk[sp] = pk; spill_pay[sp] = p8; }
        }
    }
    __syncthreads();
    int v = (t < NPBK) ? cnt_[t] : 0;
    if (t < NPBK) sc[t] = v;
    __syncthreads();
    for (int off = 1; off < NPBK; off <<= 1) {
        int w = (t < NPBK && t >= off) ? sc[t - off] : 0;
        __syncthreads();
        if (t < NPBK) sc[t] += w;
        __syncthreads();
    }
    if (t < NPBK) {
        int ex = sc[t] - v;
        int node = (b << LOG_NPBK) + t;
        if (node <= N) offsets[node] = cbeg + ex;
        cnt_[t] = ex;
    }
    __syncthreads();
    for (int i = t; i < cnt; i += 512) {
        int pk; uint2 p8;
        bool ok = true;
        if (i < CAP) { pk = spk[i]; p8 = spay[i]; }
        else {
            int sp = sbase_s + (i - CAP);
            ok = (sp < SPILL_E);
            if (ok) { pk = spill_pk[sp]; p8 = spill_pay[sp]; }
        }
        if (ok) {
            int pos = cbeg + atomicAdd(&cnt_[(pk >> 24) & (NPBK - 1)], 1);
            packed[pos] = pk;
            pay8[pos] = p8;
        }
    }
}

// --- Fallback tiers 3/4 ---
constexpr int SCAN_BLOCK = 256;
constexpr int SCAN_ITEMS = 8;
constexpr int SCAN_CHUNK = SCAN_BLOCK * SCAN_ITEMS;

__global__ void __launch_bounds__(256) hist_kernel(
        const int* __restrict__ dst, int* __restrict__ counts, int E) {
    int e = blockIdx.x * blockDim.x + threadIdx.x;
    if (e < E) atomicAdd(&counts[dst[e]], 1);
}
__global__ void __launch_bounds__(SCAN_BLOCK) block_sum_kernel(
        const int* __restrict__ counts, int* __restrict__ bsums, int N) {
    __shared__ int sdata[SCAN_BLOCK];
    int base = blockIdx.x * SCAN_CHUNK;
    int sum = 0;
    for (int j = 0; j < SCAN_ITEMS; ++j) {
        int idx = base + j * SCAN_BLOCK + threadIdx.x;
        if (idx < N) sum += counts[idx];
    }
    sdata[threadIdx.x] = sum;
    __syncthreads();
    for (int off = SCAN_BLOCK / 2; off > 0; off >>= 1) {
        if (threadIdx.x < off) sdata[threadIdx.x] += sdata[threadIdx.x + off];
        __syncthreads();
    }
    if (threadIdx.x == 0) bsums[blockIdx.x] = sdata[0];
}
__global__ void scan_bsums_kernel(int* __restrict__ bsums, int nb) {
    if (threadIdx.x == 0 && blockIdx.x == 0) {
        int acc = 0;
        for (int i = 0; i < nb; ++i) { int v = bsums[i]; bsums[i] = acc; acc += v; }
    }
}
__global__ void __launch_bounds__(SCAN_BLOCK) scan_final_kernel(
        const int* __restrict__ counts, const int* __restrict__ bsums,
        int* __restrict__ offsets, int* __restrict__ cursors, int N, int E) {
    __shared__ int sdata[SCAN_BLOCK];
    int base = blockIdx.x * SCAN_CHUNK + threadIdx.x * SCAN_ITEMS;
    int local[SCAN_ITEMS];
    int tsum = 0;
    for (int j = 0; j < SCAN_ITEMS; ++j) {
        int idx = base + j;
        int v = (idx < N) ? counts[idx] : 0;
        local[j] = tsum;
        tsum += v;
    }
    sdata[threadIdx.x] = tsum;
    __syncthreads();
    for (int off = 1; off < SCAN_BLOCK; off <<= 1) {
        int v = (threadIdx.x >= off) ? sdata[threadIdx.x - off] : 0;
        __syncthreads();
        sdata[threadIdx.x] += v;
        __syncthreads();
    }
    int excl = sdata[threadIdx.x] - tsum + bsums[blockIdx.x];
    for (int j = 0; j < SCAN_ITEMS; ++j) {
        int idx = base + j;
        if (idx < N) { int o = excl + local[j]; offsets[idx] = o; cursors[idx] = o; }
    }
    if (blockIdx.x == 0 && threadIdx.x == 0) offsets[N] = E;
}
__global__ void __launch_bounds__(256) scatter_ids_kernel(
        const int* __restrict__ dst, int* __restrict__ cursors,
        int* __restrict__ eids, int E) {
    int e = blockIdx.x * blockDim.x + threadIdx.x;
    if (e < E) { int pos = atomicAdd(&cursors[dst[e]], 1); eids[pos] = e; }
}
__global__ void __launch_bounds__(US) accum_ids_kernel(
        const float* __restrict__ x, const float* __restrict__ sh,
        const int* __restrict__ src, const int* __restrict__ offsets,
        const int* __restrict__ eids, float* __restrict__ out) {
    int n = blockIdx.x;
    int t = threadIdx.x;
    int u = t >> 2, s = t & 3;
    int beg = offsets[n], end = offsets[n + 1];
    float acc = 0.f;
    for (int i = beg; i < end; ++i) {
        int e = eids[i];
        acc += x[src[e] * U_DIM + u] * sh[e * 4 + s];
    }
    out[(size_t)n * US + t] = acc;
}
__global__ void __launch_bounds__(US) atomic_kernel(
        const float* __restrict__ x, const float* __restrict__ sh,
        const int* __restrict__ src, const int* __restrict__ dst,
        float* __restrict__ out, int E) {
    int e = blockIdx.x;
    int t = threadIdx.x;
    float v = x[src[e] * U_DIM + (t >> 2)] * sh[e * 4 + (t & 3)];
    atomicAdd(&out[(size_t)dst[e] * US + t], v);
}

extern "C" void kernel_launch(void* const* d_in, const int* in_sizes, int n_in,
                              void* d_out, int out_size, void* d_ws, size_t ws_size,
                              hipStream_t stream) {
    const float* x  = (const float*)d_in[0];
    const float* sh = (const float*)d_in[1];
    const int* src  = (const int*)d_in[2];
    const int* dst  = (const int*)d_in[3];
    float* out = (float*)d_out;

    const int E = in_sizes[2];
    const int N = in_sizes[0] / U_DIM;
    const int xn4 = in_sizes[0] / 4;
    const int egrid = (E + 255) / 256;
    const int nb = (N + SCAN_CHUNK - 1) / SCAN_CHUNK;

    const int K1 = (N + C1_NPB - 1) >> C1_LOG;
    const int KF = (N + FINE_NPB - 1) >> FINE_LOG;
    const int EPB1 = (E + C1_NBLK - 1) / C1_NBLK;
    size_t need_main = (size_t)E * 24 + (size_t)in_sizes[0] * 2 +
                       (size_t)(N + 1 + 2 * KF + 2 + K1 + 1 +
                                2 * K1 * C1_NBLK) * 4;

    const int K = (N + NPBK - 1) >> LOG_NPBK;
    const int EPB = (E + NBLK - 1) / NBLK;
    size_t need_r7 = (size_t)E * 12 + (size_t)SPILL_E * 12 + (size_t)(N + 1) * 4 +
                     (size_t)(2 * K + 2) * 4 + (size_t)(2 * K * NBLK) * 4 +
                     (size_t)in_sizes[0] * 2;
    size_t need_ids = (size_t)E * 4 + (size_t)(3 * N + 1 + nb) * 4;

    if (K1 <= C1_MAXK && KF <= KF_MAX && N <= (1 << 21) &&
        (in_sizes[0] % 4 == 0) && ws_size >= need_main) {
        uint2* pay8A   = (uint2*)d_ws;
        uint2* pay8B   = pay8A + E;
        int* packedA   = (int*)(pay8B + E);
        int* packedB   = packedA + E;
        unsigned short* xb = (unsigned short*)(packedB + E);
        int* offsets   = (int*)(xb + in_sizes[0]);
        int* ccount_f  = offsets + N + 1;
        int* fbase     = ccount_f + KF;
        int* cbase     = fbase + KF + 1;
        int* cnt       = cbase + K1 + 1;
        int* base_tab  = cnt + K1 * C1_NBLK;

        hipMemsetAsync(ccount_f, 0, sizeof(int) * (size_t)KF, stream);
        xcvt_kernel<<<(xn4 + 255) / 256, 256, 0, stream>>>(
            (const float4*)x, (ushort4*)xb, xn4);
        c1_hist_kernel<<<C1_NBLK, 1024, 0, stream>>>(dst, ccount_f, cnt,
                                                     E, KF, K1, EPB1);
        c1_scan_kernel<<<1, 1024, 0, stream>>>(ccount_f, fbase, cbase, offsets,
                                               KF, K1, N, E);
        c1_cbase_kernel<<<K1, C1_NBLK, 0, stream>>>(cnt, cbase, base_tab);
        c1_scatter_kernel<<<C1_NBLK, 1024, 0, stream>>>(dst, src, (const float4*)sh,
                                                        base_tab, pay8A, packedA,
                                                        E, K1, EPB1);
        c2_sort_kernel<<<KF, 512, 0, stream>>>(cbase, fbase, offsets,
                                               pay8A, packedA, pay8B, packedB, N);
        accum_kernel<<<(N + 15) / 16, 256, 0, stream>>>(xb, pay8B, packedB,
                                                        offsets, out, 0x1FFFFF, N);
    } else if (K <= MAXK && (in_sizes[0] % 4 == 0) && ws_size >= need_r7) {
        uint2* pay8      = (uint2*)d_ws;
        uint2* spill_pay = pay8 + E;
        int* packed      = (int*)(spill_pay + SPILL_E);
        int* spill_pk    = packed + E;
        int* offsets     = spill_pk + SPILL_E;
        int* ccount      = offsets + N + 1;
        int* cbase       = ccount + K;
        int* cnt         = cbase + K + 1;
        int* base_tab    = cnt + K * NBLK;
        int* spill_cur   = base_tab + K * NBLK;
        unsigned short* xb = (unsigned short*)(spill_cur + 1);

        hipMemsetAsync(ccount, 0, sizeof(int) * (size_t)K, stream);
        xcvt_kernel<<<(xn4 + 255) / 256, 256, 0, stream>>>(
            (const float4*)x, (ushort4*)xb, xn4);
        coarse_hist_kernel<<<NBLK, 1024, 0, stream>>>(dst, ccount, cnt, E, K, EPB);
        coarse_scan_kernel<<<1, 1024, 0, stream>>>(ccount, cbase, offsets,
                                                   spill_cur, K, N, E);
        chunk_base_kernel<<<K, NBLK, 0, stream>>>(cnt, cbase, base_tab);
        coarse_scatter_kernel<<<NBLK, 1024, 0, stream>>>(dst, src, (const float4*)sh,
                                                         base_tab, pay8, packed,
                                                         E, K, EPB);
        fine_sort_kernel<<<K, 512, 0, stream>>>(cbase, offsets, pay8, packed,
                                                spill_pay, spill_pk, spill_cur, N);
        accum_kernel<<<(N + 15) / 16, 256, 0, stream>>>(xb, pay8, packed,
                                                        offsets, out, 0xFFFFFF, N);
    } else if (ws_size >= need_ids) {
        int* eids    = (int*)d_ws;
        int* counts  = eids + E;
        int* offsets = counts + N;
        int* cursors = offsets + N + 1;
        int* bsums   = cursors + N;

        hipMemsetAsync(counts, 0, sizeof(int) * (size_t)N, stream);
        hist_kernel<<<egrid, 256, 0, stream>>>(dst, counts, E);
        block_sum_kernel<<<nb, SCAN_BLOCK, 0, stream>>>(counts, bsums, N);
        scan_bsums_kernel<<<1, 64, 0, stream>>>(bsums, nb);
        scan_final_kernel<<<nb, SCAN_BLOCK, 0, stream>>>(counts, bsums, offsets, cursors, N, E);
        scatter_ids_kernel<<<egrid, 256, 0, stream>>>(dst, cursors, eids, E);
        accum_ids_kernel<<<N, US, 0, stream>>>(x, sh, src, offsets, eids, out);
    } else {
        hipMemsetAsync(out, 0, sizeof(float) * (size_t)out_size, stream);
        atomic_kernel<<<E, US, 0, stream>>>(x, sh, src, dst, out, E);
    }
}